// Round 1
// baseline (18373.590 us; speedup 1.0000x reference)
//
#include <hip/hip_runtime.h>
#include <hip/hip_bf16.h>

typedef float  f32x4 __attribute__((ext_vector_type(4)));
typedef float  f32x2 __attribute__((ext_vector_type(2)));
typedef int    i32x4 __attribute__((ext_vector_type(4)));

#define NB   8
#define LSEQ 2048
#define DDIM 512
#define KC   16

__device__ __forceinline__ float sigmf(float x){ return 1.f/(1.f+__expf(-x)); }
__device__ __forceinline__ float tanhf_(float x){ float e=__expf(2.f*x); return 1.f - 2.f/(e+1.f); }

// ---------------- prep kernels ----------------
__global__ void k_cast(const float* __restrict__ in, __hip_bfloat16* __restrict__ out, int n){
    int i = blockIdx.x*blockDim.x + threadIdx.x;
    if(i<n) out[i] = __float2bfloat16(in[i]);
}
__global__ void k_addb(const float* __restrict__ a, const float* __restrict__ b, float* __restrict__ o, int n){
    int i = blockIdx.x*blockDim.x + threadIdx.x;
    if(i<n) o[i] = a[i]+b[i];
}
// conv_w [co][ci][11] f32 -> wt [tap][co][ci] bf16
__global__ void k_convw(const float* __restrict__ w, __hip_bfloat16* __restrict__ wt){
    int idx = blockIdx.x*blockDim.x + threadIdx.x;
    if(idx < 512*512){
        #pragma unroll
        for(int tap=0; tap<11; ++tap)
            wt[(size_t)tap*262144 + idx] = __float2bfloat16(w[(size_t)idx*11 + tap]);
    }
}

// ---------------- positions / masks ----------------
__global__ void k_poswin(const int* __restrict__ aa, int* __restrict__ pos,
                         float* __restrict__ cm, float* __restrict__ win){
    int b = blockIdx.x;
    __shared__ unsigned char fl[LSEQ];
    for(int t=threadIdx.x; t<LSEQ; t+=blockDim.x) fl[t] = (aa[b*LSEQ+t]==4) ? 1 : 0;
    __syncthreads();
    if(threadIdx.x==0){
        int c=0;
        for(int t=0; t<LSEQ && c<KC; ++t) if(fl[t]) pos[b*KC + c++] = t;
        for(; c<KC; ++c) pos[b*KC+c]=0;
    }
    for(int t=threadIdx.x; t<LSEQ; t+=blockDim.x){
        cm[b*LSEQ+t] = fl[t] ? 1.f : 0.f;
        int lo = t-5 < 0 ? 0 : t-5;
        int hi = t+5 > LSEQ-1 ? LSEQ-1 : t+5;
        float wv = 0.f;
        for(int u=lo; u<=hi; ++u) if(fl[u]) wv = 1.f;
        win[b*LSEQ+t] = wv;
    }
}

__global__ void k_gather(const float* __restrict__ hs, const int* __restrict__ pos, float* __restrict__ feats){
    int k = blockIdx.x, b = blockIdx.y;
    int p = pos[b*KC+k];
    const f32x4* src = (const f32x4*)(hs + ((size_t)b*LSEQ + p)*DDIM);
    f32x4* dst = (f32x4*)(feats + ((size_t)b*KC + k)*DDIM);
    dst[threadIdx.x] = src[threadIdx.x];   // 128 threads * 4 floats
}

// ---------------- bilinear pf[b,k,m,c] (fp32) ----------------
__global__ __launch_bounds__(256) void k_bilinear(const float* __restrict__ feats, const float* __restrict__ Wb,
                                                  const float* __restrict__ bb, float* __restrict__ pf){
    int c = blockIdx.x, b = blockIdx.y;
    __shared__ float fl[16][516];
    __shared__ float tl[16][516];
    const float* fbase = feats + (size_t)b*16*512;
    for(int i=threadIdx.x; i<2048; i+=256){
        int k = i>>7, d = (i&127)*4;
        f32x4 v = *(const f32x4*)(fbase + k*512 + d);
        fl[k][d]=v.x; fl[k][d+1]=v.y; fl[k][d+2]=v.z; fl[k][d+3]=v.w;
    }
    __syncthreads();
    int e0 = threadIdx.x*2;
    float acc0[16], acc1[16];
    #pragma unroll
    for(int k=0;k<16;k++){ acc0[k]=0.f; acc1[k]=0.f; }
    const float* wc = Wb + (size_t)c*512*512;
    for(int d=0; d<512; ++d){
        f32x2 wv = *(const f32x2*)(wc + (size_t)d*512 + e0);
        #pragma unroll
        for(int k=0;k<16;k++){ float f = fl[k][d]; acc0[k] += f*wv.x; acc1[k] += f*wv.y; }
    }
    #pragma unroll
    for(int k=0;k<16;k++){ tl[k][e0]=acc0[k]; tl[k][e0+1]=acc1[k]; }
    __syncthreads();
    int kq = threadIdx.x>>4, mq = threadIdx.x&15;
    const f32x4* tp = (const f32x4*)&tl[kq][0];
    const f32x4* fp = (const f32x4*)&fl[mq][0];
    float s = 0.f;
    #pragma unroll 8
    for(int e=0;e<128;e++){ f32x4 a=tp[e], v=fp[e]; s += a.x*v.x + a.y*v.y + a.z*v.z + a.w*v.w; }
    pf[(((size_t)b*16+kq)*16+mq)*128 + c] = s + bb[c];
}

// ---------------- classifier -> prob ----------------
__global__ __launch_bounds__(256) void k_cls(const float* __restrict__ pf, const float* __restrict__ w1,
                                             const float* __restrict__ b1, const float* __restrict__ w2,
                                             const float* __restrict__ b2, const int* __restrict__ pos,
                                             float* __restrict__ prob){
    int b = blockIdx.x;
    __shared__ float sw1[64][128];
    __shared__ float sw2[64], sb1[64];
    for(int i=threadIdx.x; i<8192; i+=256) sw1[i>>7][i&127] = w1[i];
    if(threadIdx.x<64){ sw2[threadIdx.x]=w2[threadIdx.x]; sb1[threadIdx.x]=b1[threadIdx.x]; }
    __syncthreads();
    int k = threadIdx.x>>4, m = threadIdx.x&15;
    const f32x4* pp = (const f32x4*)(pf + (((size_t)b*16+k)*16+m)*128);
    f32x4 pr[32];
    #pragma unroll
    for(int i=0;i<32;i++) pr[i] = pp[i];
    float lg = b2[0];
    for(int n=0;n<64;n++){
        const f32x4* wr = (const f32x4*)&sw1[n][0];
        float a = sb1[n];
        #pragma unroll
        for(int i=0;i<32;i++){ f32x4 wv = wr[i]; a += pr[i].x*wv.x + pr[i].y*wv.y + pr[i].z*wv.z + pr[i].w*wv.w; }
        a = fmaxf(a, 0.f);
        lg += a*sw2[n];
    }
    float p = sigmf(lg);
    int dk = pos[b*16+k]-pos[b*16+m]; if(dk<0) dk=-dk;
    if(dk<2) p *= 0.1f;
    prob[b*256 + k*16 + m] = p;
}

// ---------------- greedy matching -> sel ----------------
__global__ void k_greedy(const float* __restrict__ prob, float* __restrict__ sel){
    int b = blockIdx.x;
    __shared__ float sp[120];
    __shared__ unsigned char si[120], sj[120];
    if(threadIdx.x==0){
        int idx=0;
        for(int i=0;i<16;i++) for(int j=i+1;j<16;j++){ si[idx]=(unsigned char)i; sj[idx]=(unsigned char)j; idx++; }
    }
    for(int i=threadIdx.x;i<256;i+=blockDim.x) sel[b*256+i]=0.f;
    __syncthreads();
    for(int q=threadIdx.x;q<120;q+=blockDim.x) sp[q] = prob[b*256 + si[q]*16 + sj[q]];
    __syncthreads();
    if(threadIdx.x==0){
        bool done[120]; bool used[16];
        for(int i=0;i<120;i++) done[i]=false;
        for(int i=0;i<16;i++)  used[i]=false;
        for(int it=0; it<120; ++it){
            int bi=-1; float bp=-1e30f;
            for(int q=0;q<120;q++) if(!done[q] && sp[q]>bp){ bp=sp[q]; bi=q; }
            done[bi]=true;
            if(bp>0.5f && !used[si[bi]] && !used[sj[bi]]){
                used[si[bi]]=true; used[sj[bi]]=true;
                sel[b*256 + si[bi]*16 + sj[bi]] = 1.f;
            }
        }
    }
}

// ---------------- bf16 MFMA GEMM: Gx = A @ Bw^T + bias (out bf16) ----------------
// A [M][KD] bf16, Bw [N][KD] bf16, tile 64x64, BK=32, 4 waves
__global__ __launch_bounds__(256) void k_gemm(const __hip_bfloat16* __restrict__ A, const __hip_bfloat16* __restrict__ Bw,
                                              const float* __restrict__ bias, __hip_bfloat16* __restrict__ C,
                                              int N, int KD){
    int nt = blockIdx.x, mt = blockIdx.y;
    __shared__ __hip_bfloat16 As[64][40];
    int tid = threadIdx.x, w = tid>>6, lane = tid&63, lo = lane&15, hi = lane>>4;
    f32x4 acc[4];
    #pragma unroll
    for(int s=0;s<4;s++) acc[s] = (f32x4){0.f,0.f,0.f,0.f};
    int r = tid>>2, kc = (tid&3)*8;
    for(int kk=0; kk<KD; kk+=32){
        __syncthreads();
        *(i32x4*)(&As[r][kc]) = *(const i32x4*)(A + ((size_t)(mt*64+r))*KD + kk + kc);
        __syncthreads();
        i32x4 bq = *(const i32x4*)(Bw + ((size_t)(nt*64 + w*16 + lo))*KD + kk + hi*8);
        asm volatile("s_nop 1" ::);
        #pragma unroll
        for(int s=0;s<4;s++){
            i32x4 a = *(const i32x4*)(&As[s*16+lo][hi*8]);
            asm volatile("v_mfma_f32_16x16x32_bf16 %0, %1, %2, %0" : "+v"(acc[s]) : "v"(a), "v"(bq));
        }
    }
    asm volatile("s_nop 7\n\ts_nop 7" ::);
    #pragma unroll
    for(int s=0;s<4;s++){
        int n = nt*64 + w*16 + lo;
        #pragma unroll
        for(int rr=0;rr<4;rr++){
            int m = mt*64 + s*16 + hi*4 + rr;
            C[(size_t)m*N + n] = __float2bfloat16(acc[s][rr] + bias[n]);
        }
    }
}

// ---------------- LSTM recurrence (one WG per direction, Whh fp8-resident) ----------------
__global__ __launch_bounds__(512, 2) void k_recur(const float* __restrict__ Whh,
                                                  const __hip_bfloat16* __restrict__ Gx,
                                                  __hip_bfloat16* __restrict__ Hout, int layer){
    int dir = blockIdx.x;
    int tid = threadIdx.x, w = tid>>6, lane = tid&63, lo = lane&15, hi = lane>>4;
    __shared__ unsigned char hb[2][16][264];
    for(int i=tid; i<2*16*264/4; i+=512) ((int*)hb)[i] = 0;

    // preload B fragments: wave w owns h-slice [32w,32w+32), cols j = q*256 + w*32 + sub*16 + lo
    long bf[4][2][8];
    const float* wbase = Whh + ((size_t)(layer*2 + dir)*1024)*256;
    #pragma unroll
    for(int q=0;q<4;q++){
        #pragma unroll
        for(int sub=0; sub<2; ++sub){
            int j = q*256 + w*32 + sub*16 + lo;
            const float* wr = wbase + (size_t)j*256;
            #pragma unroll
            for(int ks=0; ks<8; ++ks){
                int k0 = ks*32 + hi*8;
                f32x4 w0 = *(const f32x4*)(wr + k0);
                f32x4 w1 = *(const f32x4*)(wr + k0 + 4);
                int a0 = __builtin_amdgcn_cvt_pk_fp8_f32(w0.x, w0.y, 0, false);
                a0 = __builtin_amdgcn_cvt_pk_fp8_f32(w0.z, w0.w, a0, true);
                int a1 = __builtin_amdgcn_cvt_pk_fp8_f32(w1.x, w1.y, 0, false);
                a1 = __builtin_amdgcn_cvt_pk_fp8_f32(w1.z, w1.w, a1, true);
                bf[q][sub][ks] = ((long)(unsigned)a1 << 32) | (unsigned)a0;
            }
        }
    }
    float cst[2][4];
    #pragma unroll
    for(int s=0;s<2;s++){ cst[s][0]=0.f; cst[s][1]=0.f; cst[s][2]=0.f; cst[s][3]=0.f; }
    __syncthreads();

    int cur = 0;
    for(int t=0; t<LSEQ; ++t){
        int tt = dir ? (LSEQ-1-t) : t;
        // A fragments from LDS (h fp8)
        long af[8];
        #pragma unroll
        for(int ks=0; ks<8; ++ks) af[ks] = *(const long*)(&hb[cur][lo][ks*32 + hi*8]);
        // Gx loads (only lanes with real batches)
        float gx[4][2][4];
        if(hi<2){
            const __hip_bfloat16* gbase = Gx + (size_t)(hi*4)*4194304 + (size_t)tt*2048 + dir*1024 + w*32 + lo;
            #pragma unroll
            for(int rr=0; rr<4; ++rr){
                const __hip_bfloat16* gb2 = gbase + (size_t)rr*4194304;
                #pragma unroll
                for(int q=0;q<4;q++){
                    #pragma unroll
                    for(int sub=0;sub<2;sub++)
                        gx[q][sub][rr] = __bfloat162float(gb2[q*256 + sub*16]);
                }
            }
        }
        f32x4 acc[4][2];
        #pragma unroll
        for(int q=0;q<4;q++){
            #pragma unroll
            for(int sub=0;sub<2;sub++) acc[q][sub] = (f32x4){0.f,0.f,0.f,0.f};
        }
        asm volatile("s_nop 1" ::);
        #pragma unroll
        for(int ks=0; ks<8; ++ks){
            #pragma unroll
            for(int q=0;q<4;q++){
                #pragma unroll
                for(int sub=0;sub<2;sub++)
                    asm volatile("v_mfma_f32_16x16x32_fp8_fp8 %0, %1, %2, %0"
                                 : "+v"(acc[q][sub]) : "v"(af[ks]), "v"(bf[q][sub][ks]));
            }
        }
        asm volatile("s_nop 7\n\ts_nop 7" ::);
        if(hi<2){
            #pragma unroll
            for(int sub=0; sub<2; ++sub){
                #pragma unroll
                for(int rr=0; rr<4; ++rr){
                    float gi = acc[0][sub][rr] + gx[0][sub][rr];
                    float gf = acc[1][sub][rr] + gx[1][sub][rr];
                    float gg = acc[2][sub][rr] + gx[2][sub][rr];
                    float go = acc[3][sub][rr] + gx[3][sub][rr];
                    float c  = sigmf(gf)*cst[sub][rr] + sigmf(gi)*tanhf_(gg);
                    cst[sub][rr] = c;
                    float h  = sigmf(go)*tanhf_(c);
                    int p  = w*32 + sub*16 + lo;
                    int bb = hi*4 + rr;
                    Hout[((size_t)bb*LSEQ + tt)*512 + dir*256 + p] = __float2bfloat16(h);
                    int pk = __builtin_amdgcn_cvt_pk_fp8_f32(h, h, 0, false);
                    hb[cur^1][bb][p] = (unsigned char)(pk & 0xff);
                }
            }
        }
        __syncthreads();
        cur ^= 1;
    }
}

// ---------------- ce = h + 0.4*opt*win + dsb*cm (bf16) ----------------
__global__ void k_ce(const float* __restrict__ hs, const __hip_bfloat16* __restrict__ opt,
                     const float* __restrict__ win, const float* __restrict__ cm,
                     const float* __restrict__ dsb, __hip_bfloat16* __restrict__ ce){
    size_t i = (size_t)blockIdx.x*blockDim.x + threadIdx.x;
    size_t base = i*4;
    if(base >= (size_t)NB*LSEQ*DDIM) return;
    int d = (int)(base & 511);
    size_t bt = base >> 9;
    float wv = win[bt]*0.4f, cv = cm[bt];
    f32x4 h = *(const f32x4*)(hs + base);
    unsigned long long uv = *(const unsigned long long*)(opt + base);
    float o0 = __uint_as_float((unsigned)(uv & 0xffffull) << 16);
    float o1 = __uint_as_float((unsigned)((uv>>16) & 0xffffull) << 16);
    float o2 = __uint_as_float((unsigned)((uv>>32) & 0xffffull) << 16);
    float o3 = __uint_as_float((unsigned)((uv>>48) & 0xffffull) << 16);
    f32x4 dv = *(const f32x4*)(dsb + d);
    ce[base+0] = __float2bfloat16(h.x + wv*o0 + dv.x*cv);
    ce[base+1] = __float2bfloat16(h.y + wv*o1 + dv.y*cv);
    ce[base+2] = __float2bfloat16(h.z + wv*o2 + dv.z*cv);
    ce[base+3] = __float2bfloat16(h.w + wv*o3 + dv.w*cv);
}

// ---------------- conv (11 taps, MFMA) + final fusion ----------------
__global__ __launch_bounds__(256) void k_conv(const __hip_bfloat16* __restrict__ ce, const __hip_bfloat16* __restrict__ wt,
                                              const float* __restrict__ convb, const float* __restrict__ hs,
                                              float* __restrict__ outp){
    int nt = blockIdx.x, mt = blockIdx.y, b = blockIdx.z;
    __shared__ __hip_bfloat16 S[74][520];
    int tid = threadIdx.x;
    for(int i=tid; i<74*64; i+=256){
        int rq = i>>6, kc = (i&63)*8;
        int tok = mt*64 - 5 + rq;
        i32x4 v = (i32x4){0,0,0,0};
        if(tok>=0 && tok<LSEQ) v = *(const i32x4*)(ce + ((size_t)b*LSEQ + tok)*512 + kc);
        *(i32x4*)(&S[rq][kc]) = v;
    }
    __syncthreads();
    int w = tid>>6, lane = tid&63, lo = lane&15, hi = lane>>4;
    f32x4 acc[4];
    #pragma unroll
    for(int s=0;s<4;s++) acc[s] = (f32x4){0.f,0.f,0.f,0.f};
    asm volatile("s_nop 1" ::);
    for(int tap=0; tap<11; ++tap){
        const __hip_bfloat16* wtp = wt + (size_t)tap*262144;
        for(int kk=0; kk<512; kk+=32){
            i32x4 a = *(const i32x4*)(&S[16*w + lo + tap][kk + hi*8]);
            #pragma unroll
            for(int s=0;s<4;s++){
                i32x4 bq = *(const i32x4*)(wtp + (size_t)(nt*64 + s*16 + lo)*512 + kk + hi*8);
                asm volatile("v_mfma_f32_16x16x32_bf16 %0, %1, %2, %0" : "+v"(acc[s]) : "v"(a), "v"(bq));
            }
        }
    }
    asm volatile("s_nop 7\n\ts_nop 7" ::);
    #pragma unroll
    for(int s=0;s<4;s++){
        int co = nt*64 + s*16 + lo;
        float cb = convb[co];
        #pragma unroll
        for(int rr=0; rr<4; ++rr){
            int row = hi*4 + rr;
            int tok = mt*64 + 16*w + row;
            size_t gi = ((size_t)b*LSEQ + tok)*512 + co;
            float h   = hs[gi];
            float cef = __bfloat162float(S[16*w + row + 5][co]);
            outp[gi] = 0.5f*h + 0.3f*cef + 0.2f*(acc[s][rr] + cb);
        }
    }
}

// ---------------- launch ----------------
extern "C" void kernel_launch(void* const* d_in, const int* in_sizes, int n_in,
                              void* d_out, int out_size, void* d_ws, size_t ws_size,
                              hipStream_t stream)
{
    (void)in_sizes; (void)n_in; (void)out_size; (void)ws_size;
    const float* hidden = (const float*)d_in[0];
    const int*   aa     = (const int*)d_in[1];
    const float* Wbil   = (const float*)d_in[2];
    const float* bbil   = (const float*)d_in[3];
    const float* w1     = (const float*)d_in[4];
    const float* b1     = (const float*)d_in[5];
    const float* w2     = (const float*)d_in[6];
    const float* b2     = (const float*)d_in[7];
    const float* Wih    = (const float*)d_in[8];
    const float* Whh    = (const float*)d_in[9];
    const float* bih    = (const float*)d_in[10];
    const float* bhh    = (const float*)d_in[11];
    const float* convw  = (const float*)d_in[12];
    const float* convb  = (const float*)d_in[13];
    const float* dsb    = (const float*)d_in[14];

    float* outp = (float*)d_out;
    float* prob = outp + (size_t)NB*LSEQ*DDIM;           // 8388608
    float* sel  = prob + NB*KC*KC;                       // +2048

    char* p = (char*)d_ws;
    auto alloc = [&](size_t bytes)->char*{ char* r = p; p += (bytes + 255) & ~(size_t)255; return r; };
    __hip_bfloat16* gx    = (__hip_bfloat16*)alloc((size_t)16384*2048*2);
    __hip_bfloat16* hbf   = (__hip_bfloat16*)alloc((size_t)NB*LSEQ*DDIM*2);
    __hip_bfloat16* wihbf = (__hip_bfloat16*)alloc((size_t)2*2048*512*2);
    float*          bias2 = (float*)        alloc((size_t)2*2048*4);
    __hip_bfloat16* out1  = (__hip_bfloat16*)alloc((size_t)NB*LSEQ*DDIM*2);
    __hip_bfloat16* out2  = (__hip_bfloat16*)alloc((size_t)NB*LSEQ*DDIM*2);
    __hip_bfloat16* cebf  = (__hip_bfloat16*)alloc((size_t)NB*LSEQ*DDIM*2);
    __hip_bfloat16* wtc   = (__hip_bfloat16*)alloc((size_t)11*512*512*2);
    float*          feats = (float*)        alloc((size_t)NB*KC*DDIM*4);
    float*          pf    = (float*)        alloc((size_t)NB*KC*KC*128*4);
    int*            pos   = (int*)          alloc((size_t)NB*KC*4);
    float*          cm    = (float*)        alloc((size_t)NB*LSEQ*4);
    float*          win   = (float*)        alloc((size_t)NB*LSEQ*4);

    // prep
    k_cast<<<(NB*LSEQ*DDIM+255)/256, 256, 0, stream>>>(hidden, hbf, NB*LSEQ*DDIM);
    k_cast<<<(2*2048*512+255)/256,   256, 0, stream>>>(Wih, wihbf, 2*2048*512);
    k_addb<<<(4096+255)/256,         256, 0, stream>>>(bih, bhh, bias2, 4096);
    k_convw<<<(512*512+255)/256,     256, 0, stream>>>(convw, wtc);

    // classifier path (fp32)
    k_poswin<<<NB, 256, 0, stream>>>(aa, pos, cm, win);
    k_gather<<<dim3(KC, NB), 128, 0, stream>>>(hidden, pos, feats);
    k_bilinear<<<dim3(128, NB), 256, 0, stream>>>(feats, Wbil, bbil, pf);
    k_cls<<<NB, 256, 0, stream>>>(pf, w1, b1, w2, b2, pos, prob);
    k_greedy<<<NB, 64, 0, stream>>>(prob, sel);

    // BiLSTM layer 1
    k_gemm<<<dim3(32, 256), 256, 0, stream>>>(hbf, wihbf, bias2, gx, 2048, 512);
    k_recur<<<2, 512, 0, stream>>>(Whh, gx, out1, 0);
    // BiLSTM layer 2
    k_gemm<<<dim3(32, 256), 256, 0, stream>>>(out1, wihbf + (size_t)2048*512, bias2 + 2048, gx, 2048, 512);
    k_recur<<<2, 512, 0, stream>>>(Whh, gx, out2, 1);

    // fusion
    k_ce<<<(NB*LSEQ*DDIM/4+255)/256, 256, 0, stream>>>(hidden, out2, win, cm, dsb, cebf);
    k_conv<<<dim3(8, 32, NB), 256, 0, stream>>>(cebf, wtc, convb, hidden, outp);
}

// Round 2
// 10246.706 us; speedup vs baseline: 1.7931x; 1.7931x over previous
//
#include <hip/hip_runtime.h>
#include <hip/hip_bf16.h>

typedef float  f32x4 __attribute__((ext_vector_type(4)));
typedef float  f32x2 __attribute__((ext_vector_type(2)));
typedef int    i32x4 __attribute__((ext_vector_type(4)));

#define NB   8
#define LSEQ 2048
#define DDIM 512
#define KC   16

__device__ __forceinline__ float rcp_(float x){ return __builtin_amdgcn_rcpf(x); }
__device__ __forceinline__ float ex2_(float x){ return __builtin_amdgcn_exp2f(x); }
__device__ __forceinline__ float sigmf(float x){ return rcp_(1.f + ex2_(x * -1.44269504f)); }
__device__ __forceinline__ float tanhf_(float x){ return 1.f - 2.f*rcp_(1.f + ex2_(x * 2.88539008f)); }

#define GLDS(gp, lp) __builtin_amdgcn_global_load_lds(                      \
    (__attribute__((address_space(1))) const void*)(gp),                   \
    (__attribute__((address_space(3))) void*)(lp), 16, 0, 0)

// ---------------- prep kernels ----------------
__global__ void k_cast(const float* __restrict__ in, __hip_bfloat16* __restrict__ out, int n){
    int i = blockIdx.x*blockDim.x + threadIdx.x;
    if(i<n) out[i] = __float2bfloat16(in[i]);
}
__global__ void k_addb(const float* __restrict__ a, const float* __restrict__ b, float* __restrict__ o, int n){
    int i = blockIdx.x*blockDim.x + threadIdx.x;
    if(i<n) o[i] = a[i]+b[i];
}
// conv_w [co][ci][11] f32 -> wt [tap][co][ci] bf16
__global__ void k_convw(const float* __restrict__ w, __hip_bfloat16* __restrict__ wt){
    int idx = blockIdx.x*blockDim.x + threadIdx.x;
    if(idx < 512*512){
        #pragma unroll
        for(int tap=0; tap<11; ++tap)
            wt[(size_t)tap*262144 + idx] = __float2bfloat16(w[(size_t)idx*11 + tap]);
    }
}

// ---------------- positions / masks ----------------
__global__ void k_poswin(const int* __restrict__ aa, int* __restrict__ pos,
                         float* __restrict__ cm, float* __restrict__ win){
    int b = blockIdx.x;
    __shared__ unsigned char fl[LSEQ];
    for(int t=threadIdx.x; t<LSEQ; t+=blockDim.x) fl[t] = (aa[b*LSEQ+t]==4) ? 1 : 0;
    __syncthreads();
    if(threadIdx.x==0){
        int c=0;
        for(int t=0; t<LSEQ && c<KC; ++t) if(fl[t]) pos[b*KC + c++] = t;
        for(; c<KC; ++c) pos[b*KC+c]=0;
    }
    for(int t=threadIdx.x; t<LSEQ; t+=blockDim.x){
        cm[b*LSEQ+t] = fl[t] ? 1.f : 0.f;
        int lo = t-5 < 0 ? 0 : t-5;
        int hi = t+5 > LSEQ-1 ? LSEQ-1 : t+5;
        float wv = 0.f;
        for(int u=lo; u<=hi; ++u) if(fl[u]) wv = 1.f;
        win[b*LSEQ+t] = wv;
    }
}

__global__ void k_gather(const float* __restrict__ hs, const int* __restrict__ pos, float* __restrict__ feats){
    int k = blockIdx.x, b = blockIdx.y;
    int p = pos[b*KC+k];
    const f32x4* src = (const f32x4*)(hs + ((size_t)b*LSEQ + p)*DDIM);
    f32x4* dst = (f32x4*)(feats + ((size_t)b*KC + k)*DDIM);
    dst[threadIdx.x] = src[threadIdx.x];   // 128 threads * 4 floats
}

// ---------------- bilinear pf[b,k,m,c] (fp32) ----------------
__global__ __launch_bounds__(256) void k_bilinear(const float* __restrict__ feats, const float* __restrict__ Wb,
                                                  const float* __restrict__ bb, float* __restrict__ pf){
    int c = blockIdx.x, b = blockIdx.y;
    __shared__ float fl[16][516];
    __shared__ float tl[16][516];
    const float* fbase = feats + (size_t)b*16*512;
    for(int i=threadIdx.x; i<2048; i+=256){
        int k = i>>7, d = (i&127)*4;
        f32x4 v = *(const f32x4*)(fbase + k*512 + d);
        fl[k][d]=v.x; fl[k][d+1]=v.y; fl[k][d+2]=v.z; fl[k][d+3]=v.w;
    }
    __syncthreads();
    int e0 = threadIdx.x*2;
    float acc0[16], acc1[16];
    #pragma unroll
    for(int k=0;k<16;k++){ acc0[k]=0.f; acc1[k]=0.f; }
    const float* wc = Wb + (size_t)c*512*512;
    for(int d=0; d<512; ++d){
        f32x2 wv = *(const f32x2*)(wc + (size_t)d*512 + e0);
        #pragma unroll
        for(int k=0;k<16;k++){ float f = fl[k][d]; acc0[k] += f*wv.x; acc1[k] += f*wv.y; }
    }
    #pragma unroll
    for(int k=0;k<16;k++){ tl[k][e0]=acc0[k]; tl[k][e0+1]=acc1[k]; }
    __syncthreads();
    int kq = threadIdx.x>>4, mq = threadIdx.x&15;
    const f32x4* tp = (const f32x4*)&tl[kq][0];
    const f32x4* fp = (const f32x4*)&fl[mq][0];
    float s = 0.f;
    #pragma unroll 8
    for(int e=0;e<128;e++){ f32x4 a=tp[e], v=fp[e]; s += a.x*v.x + a.y*v.y + a.z*v.z + a.w*v.w; }
    pf[(((size_t)b*16+kq)*16+mq)*128 + c] = s + bb[c];
}

// ---------------- classifier -> prob ----------------
__global__ __launch_bounds__(256) void k_cls(const float* __restrict__ pf, const float* __restrict__ w1,
                                             const float* __restrict__ b1, const float* __restrict__ w2,
                                             const float* __restrict__ b2, const int* __restrict__ pos,
                                             float* __restrict__ prob){
    int b = blockIdx.x;
    __shared__ float sw1[64][128];
    __shared__ float sw2[64], sb1[64];
    for(int i=threadIdx.x; i<8192; i+=256) sw1[i>>7][i&127] = w1[i];
    if(threadIdx.x<64){ sw2[threadIdx.x]=w2[threadIdx.x]; sb1[threadIdx.x]=b1[threadIdx.x]; }
    __syncthreads();
    int k = threadIdx.x>>4, m = threadIdx.x&15;
    const f32x4* pp = (const f32x4*)(pf + (((size_t)b*16+k)*16+m)*128);
    f32x4 pr[32];
    #pragma unroll
    for(int i=0;i<32;i++) pr[i] = pp[i];
    float lg = b2[0];
    for(int n=0;n<64;n++){
        const f32x4* wr = (const f32x4*)&sw1[n][0];
        float a = sb1[n];
        #pragma unroll
        for(int i=0;i<32;i++){ f32x4 wv = wr[i]; a += pr[i].x*wv.x + pr[i].y*wv.y + pr[i].z*wv.z + pr[i].w*wv.w; }
        a = fmaxf(a, 0.f);
        lg += a*sw2[n];
    }
    float p = rcp_(1.f + ex2_(lg * -1.44269504f));
    int dk = pos[b*16+k]-pos[b*16+m]; if(dk<0) dk=-dk;
    if(dk<2) p *= 0.1f;
    prob[b*256 + k*16 + m] = p;
}

// ---------------- greedy matching -> sel ----------------
__global__ void k_greedy(const float* __restrict__ prob, float* __restrict__ sel){
    int b = blockIdx.x;
    __shared__ float sp[120];
    __shared__ unsigned char si[120], sj[120];
    if(threadIdx.x==0){
        int idx=0;
        for(int i=0;i<16;i++) for(int j=i+1;j<16;j++){ si[idx]=(unsigned char)i; sj[idx]=(unsigned char)j; idx++; }
    }
    for(int i=threadIdx.x;i<256;i+=blockDim.x) sel[b*256+i]=0.f;
    __syncthreads();
    for(int q=threadIdx.x;q<120;q+=blockDim.x) sp[q] = prob[b*256 + si[q]*16 + sj[q]];
    __syncthreads();
    if(threadIdx.x==0){
        bool done[120]; bool used[16];
        for(int i=0;i<120;i++) done[i]=false;
        for(int i=0;i<16;i++)  used[i]=false;
        for(int it=0; it<120; ++it){
            int bi=-1; float bp=-1e30f;
            for(int q=0;q<120;q++) if(!done[q] && sp[q]>bp){ bp=sp[q]; bi=q; }
            done[bi]=true;
            if(bp>0.5f && !used[si[bi]] && !used[sj[bi]]){
                used[si[bi]]=true; used[sj[bi]]=true;
                sel[b*256 + si[bi]*16 + sj[bi]] = 1.f;
            }
        }
    }
}

// ---------------- bf16 MFMA GEMM: Gx = A @ Bw^T + bias (out bf16) ----------------
__global__ __launch_bounds__(256) void k_gemm(const __hip_bfloat16* __restrict__ A, const __hip_bfloat16* __restrict__ Bw,
                                              const float* __restrict__ bias, __hip_bfloat16* __restrict__ C,
                                              int N, int KD){
    int nt = blockIdx.x, mt = blockIdx.y;
    __shared__ __hip_bfloat16 As[64][40];
    int tid = threadIdx.x, w = tid>>6, lane = tid&63, lo = lane&15, hi = lane>>4;
    f32x4 acc[4];
    #pragma unroll
    for(int s=0;s<4;s++) acc[s] = (f32x4){0.f,0.f,0.f,0.f};
    int r = tid>>2, kc = (tid&3)*8;
    for(int kk=0; kk<KD; kk+=32){
        __syncthreads();
        *(i32x4*)(&As[r][kc]) = *(const i32x4*)(A + ((size_t)(mt*64+r))*KD + kk + kc);
        __syncthreads();
        i32x4 bq = *(const i32x4*)(Bw + ((size_t)(nt*64 + w*16 + lo))*KD + kk + hi*8);
        asm volatile("s_nop 1" ::);
        #pragma unroll
        for(int s=0;s<4;s++){
            i32x4 a = *(const i32x4*)(&As[s*16+lo][hi*8]);
            asm volatile("v_mfma_f32_16x16x32_bf16 %0, %1, %2, %0" : "+v"(acc[s]) : "v"(a), "v"(bq));
        }
    }
    asm volatile("s_nop 7\n\ts_nop 7" ::);
    #pragma unroll
    for(int s=0;s<4;s++){
        int n = nt*64 + w*16 + lo;
        #pragma unroll
        for(int rr=0;rr<4;rr++){
            int m = mt*64 + s*16 + hi*4 + rr;
            C[(size_t)m*N + n] = __float2bfloat16(acc[s][rr] + bias[n]);
        }
    }
}

// ---------------- LSTM recurrence ----------------
// One 512-thread WG per direction. Whh fp8 resident in AGPRs ("a" operands).
// Per step: prefetch Gx(t+1)->LDS (global_load_lds, dbuf, vmcnt(2)),
// MFMA h@Whh^T, redistribute gate accs through LDS, epilogue spread over
// ALL 512 lanes (wave=batch, lane=4 h-indices), coalesced outputs.
__global__ __launch_bounds__(512, 2) void k_recur(const float* __restrict__ Whh,
                                                  const __hip_bfloat16* __restrict__ Gx,
                                                  __hip_bfloat16* __restrict__ Hout, int layer){
    const int dir = blockIdx.x;
    const int tid = threadIdx.x, w = tid>>6, lane = tid&63, lo = lane&15, hi = lane>>4;
    __shared__ unsigned char hb[2][16][264];     // h in fp8, rows 8..15 stay zero
    __shared__ float gacc[8][1024];              // gate accs f32 [batch][gate]
    __shared__ __hip_bfloat16 gxs[2][8][1024];   // staged Gx rows [buf][batch][gate]
    __shared__ float lds_pad[2048];              // pad >80KB: one block per CU
    if(Gx == nullptr) ((volatile float*)lds_pad)[0] = 1.f;

    for(int i=tid; i<2112; i+=512) ((int*)hb)[i] = 0;

    // preload Whh fp8 fragments (held in AGPRs)
    long bf[4][2][8];
    const float* wbase = Whh + ((size_t)(layer*2 + dir)*1024)*256;
    #pragma unroll
    for(int q=0;q<4;q++){
        #pragma unroll
        for(int sub=0; sub<2; ++sub){
            int j = q*256 + w*32 + sub*16 + lo;
            const float* wr = wbase + (size_t)j*256;
            #pragma unroll
            for(int ks=0; ks<8; ++ks){
                int k0 = ks*32 + hi*8;
                f32x4 w0 = *(const f32x4*)(wr + k0);
                f32x4 w1 = *(const f32x4*)(wr + k0 + 4);
                int a0 = __builtin_amdgcn_cvt_pk_fp8_f32(w0.x, w0.y, 0, false);
                a0 = __builtin_amdgcn_cvt_pk_fp8_f32(w0.z, w0.w, a0, true);
                int a1 = __builtin_amdgcn_cvt_pk_fp8_f32(w1.x, w1.y, 0, false);
                a1 = __builtin_amdgcn_cvt_pk_fp8_f32(w1.z, w1.w, a1, true);
                bf[q][sub][ks] = ((long)(unsigned)a1 << 32) | (unsigned)a0;
            }
        }
    }
    float cst[4] = {0.f, 0.f, 0.f, 0.f};
    const int j4 = lane*4;

    // prologue: stage Gx row for t=0
    {
        int t0 = dir ? (LSEQ-1) : 0;
        const __hip_bfloat16* src = Gx + (size_t)w*4194304 + (size_t)t0*2048 + dir*1024;
        GLDS(src + lane*8, &gxs[0][w][0]);
        GLDS(src + 512 + lane*8, &gxs[0][w][512]);
    }
    asm volatile("s_waitcnt lgkmcnt(0)" ::: "memory");
    __builtin_amdgcn_s_barrier();
    __builtin_amdgcn_sched_barrier(0);

    int cur = 0;
    for(int t=0; t<LSEQ; ++t){
        const int tt = dir ? (LSEQ-1-t) : t;
        const int nxt = cur^1;
        // phase 1: prefetch Gx for t+1 (clamped dummy at last step)
        {
            int tn_t = (t+1 < LSEQ) ? (t+1) : (LSEQ-1);
            int tn = dir ? (LSEQ-1-tn_t) : tn_t;
            const __hip_bfloat16* src = Gx + (size_t)w*4194304 + (size_t)tn*2048 + dir*1024;
            GLDS(src + lane*8, &gxs[nxt][w][0]);
            GLDS(src + 512 + lane*8, &gxs[nxt][w][512]);
        }
        // phase 2: A fragments (h fp8 from LDS)
        long af[8];
        #pragma unroll
        for(int ks=0; ks<8; ++ks) af[ks] = *(const long*)(&hb[cur][lo][ks*32 + hi*8]);
        // phase 3: MFMA  (B from AGPR)
        f32x4 acc[4][2];
        #pragma unroll
        for(int q=0;q<4;q++){
            #pragma unroll
            for(int sub=0;sub<2;sub++) acc[q][sub] = (f32x4){0.f,0.f,0.f,0.f};
        }
        asm volatile("s_nop 1" ::);
        #pragma unroll
        for(int ks=0; ks<8; ++ks){
            #pragma unroll
            for(int q=0;q<4;q++){
                #pragma unroll
                for(int sub=0;sub<2;sub++)
                    asm volatile("v_mfma_f32_16x16x32_fp8_fp8 %0, %1, %2, %0"
                                 : "+v"(acc[q][sub]) : "v"(af[ks]), "a"(bf[q][sub][ks]));
            }
        }
        asm volatile("s_nop 7\n\ts_nop 7" ::);
        // phase 4: scatter gate accs to LDS (batch rows 0..7 only)
        if(hi<2){
            int b0 = hi*4;
            #pragma unroll
            for(int q=0;q<4;q++){
                #pragma unroll
                for(int sub=0;sub<2;sub++){
                    int jg = q*256 + w*32 + sub*16 + lo;
                    #pragma unroll
                    for(int rr=0;rr<4;rr++) gacc[b0+rr][jg] = acc[q][sub][rr];
                }
            }
        }
        // phase 5: make gacc visible
        asm volatile("s_waitcnt lgkmcnt(0)" ::: "memory");
        __builtin_amdgcn_s_barrier();
        __builtin_amdgcn_sched_barrier(0);
        // phase 6: ensure gxs[cur] staged (2 newest loads = next-step prefetch)
        asm volatile("s_waitcnt vmcnt(2)" ::: "memory");
        // phase 7: epilogue — all lanes: batch w, h indices j4..j4+3
        {
            f32x4 gI = *(const f32x4*)&gacc[w][      j4];
            f32x4 gF = *(const f32x4*)&gacc[w][256 + j4];
            f32x4 gG = *(const f32x4*)&gacc[w][512 + j4];
            f32x4 gO = *(const f32x4*)&gacc[w][768 + j4];
            unsigned long long xI = *(const unsigned long long*)&gxs[cur][w][      j4];
            unsigned long long xF = *(const unsigned long long*)&gxs[cur][w][256 + j4];
            unsigned long long xG = *(const unsigned long long*)&gxs[cur][w][512 + j4];
            unsigned long long xO = *(const unsigned long long*)&gxs[cur][w][768 + j4];
            float hh[4];
            #pragma unroll
            for(int jj=0; jj<4; ++jj){
                int sh = jj*16;
                float gi = gI[jj] + __uint_as_float((unsigned)((xI>>sh) & 0xffffull) << 16);
                float gf = gF[jj] + __uint_as_float((unsigned)((xF>>sh) & 0xffffull) << 16);
                float gg = gG[jj] + __uint_as_float((unsigned)((xG>>sh) & 0xffffull) << 16);
                float go = gO[jj] + __uint_as_float((unsigned)((xO>>sh) & 0xffffull) << 16);
                float c  = sigmf(gf)*cst[jj] + sigmf(gi)*tanhf_(gg);
                cst[jj] = c;
                hh[jj]  = sigmf(go)*tanhf_(c);
            }
            int pk = __builtin_amdgcn_cvt_pk_fp8_f32(hh[0], hh[1], 0, false);
            pk = __builtin_amdgcn_cvt_pk_fp8_f32(hh[2], hh[3], pk, true);
            *(unsigned int*)&hb[nxt][w][j4] = (unsigned int)pk;
            __hip_bfloat16 b0 = __float2bfloat16(hh[0]), b1 = __float2bfloat16(hh[1]);
            __hip_bfloat16 b2 = __float2bfloat16(hh[2]), b3 = __float2bfloat16(hh[3]);
            uint2 hv;
            hv.x = (unsigned)*(unsigned short*)&b0 | ((unsigned)*(unsigned short*)&b1 << 16);
            hv.y = (unsigned)*(unsigned short*)&b2 | ((unsigned)*(unsigned short*)&b3 << 16);
            *(uint2*)&Hout[((size_t)w*LSEQ + tt)*512 + dir*256 + j4] = hv;
        }
        // phase 8: hb[nxt] + gacc reads drained before next step
        asm volatile("s_waitcnt lgkmcnt(0)" ::: "memory");
        __builtin_amdgcn_s_barrier();
        __builtin_amdgcn_sched_barrier(0);
        cur = nxt;
    }
}

// ---------------- ce = h + 0.4*opt*win + dsb*cm (bf16) ----------------
__global__ void k_ce(const float* __restrict__ hs, const __hip_bfloat16* __restrict__ opt,
                     const float* __restrict__ win, const float* __restrict__ cm,
                     const float* __restrict__ dsb, __hip_bfloat16* __restrict__ ce){
    size_t i = (size_t)blockIdx.x*blockDim.x + threadIdx.x;
    size_t base = i*4;
    if(base >= (size_t)NB*LSEQ*DDIM) return;
    int d = (int)(base & 511);
    size_t bt = base >> 9;
    float wv = win[bt]*0.4f, cv = cm[bt];
    f32x4 h = *(const f32x4*)(hs + base);
    unsigned long long uv = *(const unsigned long long*)(opt + base);
    float o0 = __uint_as_float((unsigned)(uv & 0xffffull) << 16);
    float o1 = __uint_as_float((unsigned)((uv>>16) & 0xffffull) << 16);
    float o2 = __uint_as_float((unsigned)((uv>>32) & 0xffffull) << 16);
    float o3 = __uint_as_float((unsigned)((uv>>48) & 0xffffull) << 16);
    f32x4 dv = *(const f32x4*)(dsb + d);
    ce[base+0] = __float2bfloat16(h.x + wv*o0 + dv.x*cv);
    ce[base+1] = __float2bfloat16(h.y + wv*o1 + dv.y*cv);
    ce[base+2] = __float2bfloat16(h.z + wv*o2 + dv.z*cv);
    ce[base+3] = __float2bfloat16(h.w + wv*o3 + dv.w*cv);
}

// ---------------- conv (11 taps, MFMA) + final fusion ----------------
__global__ __launch_bounds__(256) void k_conv(const __hip_bfloat16* __restrict__ ce, const __hip_bfloat16* __restrict__ wt,
                                              const float* __restrict__ convb, const float* __restrict__ hs,
                                              float* __restrict__ outp){
    int nt = blockIdx.x, mt = blockIdx.y, b = blockIdx.z;
    __shared__ __hip_bfloat16 S[74][520];
    int tid = threadIdx.x;
    for(int i=tid; i<74*64; i+=256){
        int rq = i>>6, kc = (i&63)*8;
        int tok = mt*64 - 5 + rq;
        i32x4 v = (i32x4){0,0,0,0};
        if(tok>=0 && tok<LSEQ) v = *(const i32x4*)(ce + ((size_t)b*LSEQ + tok)*512 + kc);
        *(i32x4*)(&S[rq][kc]) = v;
    }
    __syncthreads();
    int w = tid>>6, lane = tid&63, lo = lane&15, hi = lane>>4;
    f32x4 acc[4];
    #pragma unroll
    for(int s=0;s<4;s++) acc[s] = (f32x4){0.f,0.f,0.f,0.f};
    asm volatile("s_nop 1" ::);
    for(int tap=0; tap<11; ++tap){
        const __hip_bfloat16* wtp = wt + (size_t)tap*262144;
        for(int kk=0; kk<512; kk+=32){
            i32x4 a = *(const i32x4*)(&S[16*w + lo + tap][kk + hi*8]);
            #pragma unroll
            for(int s=0;s<4;s++){
                i32x4 bq = *(const i32x4*)(wtp + (size_t)(nt*64 + s*16 + lo)*512 + kk + hi*8);
                asm volatile("v_mfma_f32_16x16x32_bf16 %0, %1, %2, %0" : "+v"(acc[s]) : "v"(a), "v"(bq));
            }
        }
    }
    asm volatile("s_nop 7\n\ts_nop 7" ::);
    #pragma unroll
    for(int s=0;s<4;s++){
        int co = nt*64 + s*16 + lo;
        float cb = convb[co];
        #pragma unroll
        for(int rr=0; rr<4; ++rr){
            int row = hi*4 + rr;
            int tok = mt*64 + 16*w + row;
            size_t gi = ((size_t)b*LSEQ + tok)*512 + co;
            float h   = hs[gi];
            float cef = __bfloat162float(S[16*w + row + 5][co]);
            outp[gi] = 0.5f*h + 0.3f*cef + 0.2f*(acc[s][rr] + cb);
        }
    }
}

// ---------------- launch ----------------
extern "C" void kernel_launch(void* const* d_in, const int* in_sizes, int n_in,
                              void* d_out, int out_size, void* d_ws, size_t ws_size,
                              hipStream_t stream)
{
    (void)in_sizes; (void)n_in; (void)out_size; (void)ws_size;
    const float* hidden = (const float*)d_in[0];
    const int*   aa     = (const int*)d_in[1];
    const float* Wbil   = (const float*)d_in[2];
    const float* bbil   = (const float*)d_in[3];
    const float* w1     = (const float*)d_in[4];
    const float* b1     = (const float*)d_in[5];
    const float* w2     = (const float*)d_in[6];
    const float* b2     = (const float*)d_in[7];
    const float* Wih    = (const float*)d_in[8];
    const float* Whh    = (const float*)d_in[9];
    const float* bih    = (const float*)d_in[10];
    const float* bhh    = (const float*)d_in[11];
    const float* convw  = (const float*)d_in[12];
    const float* convb  = (const float*)d_in[13];
    const float* dsb    = (const float*)d_in[14];

    float* outp = (float*)d_out;
    float* prob = outp + (size_t)NB*LSEQ*DDIM;           // 8388608
    float* sel  = prob + NB*KC*KC;                       // +2048

    char* p = (char*)d_ws;
    auto alloc = [&](size_t bytes)->char*{ char* r = p; p += (bytes + 255) & ~(size_t)255; return r; };
    __hip_bfloat16* gx    = (__hip_bfloat16*)alloc((size_t)16384*2048*2);
    __hip_bfloat16* hbf   = (__hip_bfloat16*)alloc((size_t)NB*LSEQ*DDIM*2);
    __hip_bfloat16* wihbf = (__hip_bfloat16*)alloc((size_t)2*2048*512*2);
    float*          bias2 = (float*)        alloc((size_t)2*2048*4);
    __hip_bfloat16* out1  = (__hip_bfloat16*)alloc((size_t)NB*LSEQ*DDIM*2);
    __hip_bfloat16* out2  = (__hip_bfloat16*)alloc((size_t)NB*LSEQ*DDIM*2);
    __hip_bfloat16* cebf  = (__hip_bfloat16*)alloc((size_t)NB*LSEQ*DDIM*2);
    __hip_bfloat16* wtc   = (__hip_bfloat16*)alloc((size_t)11*512*512*2);
    float*          feats = (float*)        alloc((size_t)NB*KC*DDIM*4);
    float*          pf    = (float*)        alloc((size_t)NB*KC*KC*128*4);
    int*            pos   = (int*)          alloc((size_t)NB*KC*4);
    float*          cm    = (float*)        alloc((size_t)NB*LSEQ*4);
    float*          win   = (float*)        alloc((size_t)NB*LSEQ*4);

    // prep
    k_cast<<<(NB*LSEQ*DDIM+255)/256, 256, 0, stream>>>(hidden, hbf, NB*LSEQ*DDIM);
    k_cast<<<(2*2048*512+255)/256,   256, 0, stream>>>(Wih, wihbf, 2*2048*512);
    k_addb<<<(4096+255)/256,         256, 0, stream>>>(bih, bhh, bias2, 4096);
    k_convw<<<(512*512+255)/256,     256, 0, stream>>>(convw, wtc);

    // classifier path (fp32)
    k_poswin<<<NB, 256, 0, stream>>>(aa, pos, cm, win);
    k_gather<<<dim3(KC, NB), 128, 0, stream>>>(hidden, pos, feats);
    k_bilinear<<<dim3(128, NB), 256, 0, stream>>>(feats, Wbil, bbil, pf);
    k_cls<<<NB, 256, 0, stream>>>(pf, w1, b1, w2, b2, pos, prob);
    k_greedy<<<NB, 64, 0, stream>>>(prob, sel);

    // BiLSTM layer 1
    k_gemm<<<dim3(32, 256), 256, 0, stream>>>(hbf, wihbf, bias2, gx, 2048, 512);
    k_recur<<<2, 512, 0, stream>>>(Whh, gx, out1, 0);
    // BiLSTM layer 2
    k_gemm<<<dim3(32, 256), 256, 0, stream>>>(out1, wihbf + (size_t)2048*512, bias2 + 2048, gx, 2048, 512);
    k_recur<<<2, 512, 0, stream>>>(Whh, gx, out2, 1);

    // fusion
    k_ce<<<(NB*LSEQ*DDIM/4+255)/256, 256, 0, stream>>>(hidden, out2, win, cm, dsb, cebf);
    k_conv<<<dim3(8, 32, NB), 256, 0, stream>>>(cebf, wtc, convb, hidden, outp);
}

// Round 3
// 8097.539 us; speedup vs baseline: 2.2690x; 1.2654x over previous
//
#include <hip/hip_runtime.h>
#include <hip/hip_bf16.h>

typedef float  f32x4 __attribute__((ext_vector_type(4)));
typedef float  f32x2 __attribute__((ext_vector_type(2)));
typedef int    i32x4 __attribute__((ext_vector_type(4)));
typedef int    i32x8 __attribute__((ext_vector_type(8)));

#define NB   8
#define LSEQ 2048
#define DDIM 512
#define KC   16

__device__ __forceinline__ float rcp_(float x){ return __builtin_amdgcn_rcpf(x); }
__device__ __forceinline__ float ex2_(float x){ return __builtin_amdgcn_exp2f(x); }
__device__ __forceinline__ float clamp60(float x){ return fminf(fmaxf(x, -60.f), 60.f); }
__device__ __forceinline__ float bf16u(unsigned long long u){
    return __uint_as_float(((unsigned)u & 0xffffu) << 16);
}

#define GLDS(gp, lp) __builtin_amdgcn_global_load_lds(                      \
    (__attribute__((address_space(1))) const void*)(gp),                   \
    (__attribute__((address_space(3))) void*)(lp), 16, 0, 0)

// ---------------- prep kernels ----------------
__global__ void k_cast(const float* __restrict__ in, __hip_bfloat16* __restrict__ out, int n){
    int i = blockIdx.x*blockDim.x + threadIdx.x;
    if(i<n) out[i] = __float2bfloat16(in[i]);
}
__global__ void k_addb(const float* __restrict__ a, const float* __restrict__ b, float* __restrict__ o, int n){
    int i = blockIdx.x*blockDim.x + threadIdx.x;
    if(i<n) o[i] = a[i]+b[i];
}
// conv_w [co][ci][11] f32 -> wt [tap][co][ci] bf16
__global__ void k_convw(const float* __restrict__ w, __hip_bfloat16* __restrict__ wt){
    int idx = blockIdx.x*blockDim.x + threadIdx.x;
    if(idx < 512*512){
        #pragma unroll
        for(int tap=0; tap<11; ++tap)
            wt[(size_t)tap*262144 + idx] = __float2bfloat16(w[(size_t)idx*11 + tap]);
    }
}

// ---------------- positions / masks ----------------
__global__ void k_poswin(const int* __restrict__ aa, int* __restrict__ pos,
                         float* __restrict__ cm, float* __restrict__ win){
    int b = blockIdx.x;
    __shared__ unsigned char fl[LSEQ];
    for(int t=threadIdx.x; t<LSEQ; t+=blockDim.x) fl[t] = (aa[b*LSEQ+t]==4) ? 1 : 0;
    __syncthreads();
    if(threadIdx.x==0){
        int c=0;
        for(int t=0; t<LSEQ && c<KC; ++t) if(fl[t]) pos[b*KC + c++] = t;
        for(; c<KC; ++c) pos[b*KC+c]=0;
    }
    for(int t=threadIdx.x; t<LSEQ; t+=blockDim.x){
        cm[b*LSEQ+t] = fl[t] ? 1.f : 0.f;
        int lo = t-5 < 0 ? 0 : t-5;
        int hi = t+5 > LSEQ-1 ? LSEQ-1 : t+5;
        float wv = 0.f;
        for(int u=lo; u<=hi; ++u) if(fl[u]) wv = 1.f;
        win[b*LSEQ+t] = wv;
    }
}

__global__ void k_gather(const float* __restrict__ hs, const int* __restrict__ pos, float* __restrict__ feats){
    int k = blockIdx.x, b = blockIdx.y;
    int p = pos[b*KC+k];
    const f32x4* src = (const f32x4*)(hs + ((size_t)b*LSEQ + p)*DDIM);
    f32x4* dst = (f32x4*)(feats + ((size_t)b*KC + k)*DDIM);
    dst[threadIdx.x] = src[threadIdx.x];   // 128 threads * 4 floats
}

// ---------------- bilinear pf[b,k,m,c] (fp32) ----------------
__global__ __launch_bounds__(256) void k_bilinear(const float* __restrict__ feats, const float* __restrict__ Wb,
                                                  const float* __restrict__ bb, float* __restrict__ pf){
    int c = blockIdx.x, b = blockIdx.y;
    __shared__ float fl[16][516];
    __shared__ float tl[16][516];
    const float* fbase = feats + (size_t)b*16*512;
    for(int i=threadIdx.x; i<2048; i+=256){
        int k = i>>7, d = (i&127)*4;
        f32x4 v = *(const f32x4*)(fbase + k*512 + d);
        fl[k][d]=v.x; fl[k][d+1]=v.y; fl[k][d+2]=v.z; fl[k][d+3]=v.w;
    }
    __syncthreads();
    int e0 = threadIdx.x*2;
    float acc0[16], acc1[16];
    #pragma unroll
    for(int k=0;k<16;k++){ acc0[k]=0.f; acc1[k]=0.f; }
    const float* wc = Wb + (size_t)c*512*512;
    for(int d=0; d<512; ++d){
        f32x2 wv = *(const f32x2*)(wc + (size_t)d*512 + e0);
        #pragma unroll
        for(int k=0;k<16;k++){ float f = fl[k][d]; acc0[k] += f*wv.x; acc1[k] += f*wv.y; }
    }
    #pragma unroll
    for(int k=0;k<16;k++){ tl[k][e0]=acc0[k]; tl[k][e0+1]=acc1[k]; }
    __syncthreads();
    int kq = threadIdx.x>>4, mq = threadIdx.x&15;
    const f32x4* tp = (const f32x4*)&tl[kq][0];
    const f32x4* fp = (const f32x4*)&fl[mq][0];
    float s = 0.f;
    #pragma unroll 8
    for(int e=0;e<128;e++){ f32x4 a=tp[e], v=fp[e]; s += a.x*v.x + a.y*v.y + a.z*v.z + a.w*v.w; }
    pf[(((size_t)b*16+kq)*16+mq)*128 + c] = s + bb[c];
}

// ---------------- classifier -> prob ----------------
__global__ __launch_bounds__(256) void k_cls(const float* __restrict__ pf, const float* __restrict__ w1,
                                             const float* __restrict__ b1, const float* __restrict__ w2,
                                             const float* __restrict__ b2, const int* __restrict__ pos,
                                             float* __restrict__ prob){
    int b = blockIdx.x;
    __shared__ float sw1[64][128];
    __shared__ float sw2[64], sb1[64];
    for(int i=threadIdx.x; i<8192; i+=256) sw1[i>>7][i&127] = w1[i];
    if(threadIdx.x<64){ sw2[threadIdx.x]=w2[threadIdx.x]; sb1[threadIdx.x]=b1[threadIdx.x]; }
    __syncthreads();
    int k = threadIdx.x>>4, m = threadIdx.x&15;
    const f32x4* pp = (const f32x4*)(pf + (((size_t)b*16+k)*16+m)*128);
    f32x4 pr[32];
    #pragma unroll
    for(int i=0;i<32;i++) pr[i] = pp[i];
    float lg = b2[0];
    for(int n=0;n<64;n++){
        const f32x4* wr = (const f32x4*)&sw1[n][0];
        float a = sb1[n];
        #pragma unroll
        for(int i=0;i<32;i++){ f32x4 wv = wr[i]; a += pr[i].x*wv.x + pr[i].y*wv.y + pr[i].z*wv.z + pr[i].w*wv.w; }
        a = fmaxf(a, 0.f);
        lg += a*sw2[n];
    }
    float p = rcp_(1.f + ex2_(lg * -1.44269504f));
    int dk = pos[b*16+k]-pos[b*16+m]; if(dk<0) dk=-dk;
    if(dk<2) p *= 0.1f;
    prob[b*256 + k*16 + m] = p;
}

// ---------------- greedy matching -> sel ----------------
__global__ void k_greedy(const float* __restrict__ prob, float* __restrict__ sel){
    int b = blockIdx.x;
    __shared__ float sp[120];
    __shared__ unsigned char si[120], sj[120];
    if(threadIdx.x==0){
        int idx=0;
        for(int i=0;i<16;i++) for(int j=i+1;j<16;j++){ si[idx]=(unsigned char)i; sj[idx]=(unsigned char)j; idx++; }
    }
    for(int i=threadIdx.x;i<256;i+=blockDim.x) sel[b*256+i]=0.f;
    __syncthreads();
    for(int q=threadIdx.x;q<120;q+=blockDim.x) sp[q] = prob[b*256 + si[q]*16 + sj[q]];
    __syncthreads();
    if(threadIdx.x==0){
        bool done[120]; bool used[16];
        for(int i=0;i<120;i++) done[i]=false;
        for(int i=0;i<16;i++)  used[i]=false;
        for(int it=0; it<120; ++it){
            int bi=-1; float bp=-1e30f;
            for(int q=0;q<120;q++) if(!done[q] && sp[q]>bp){ bp=sp[q]; bi=q; }
            done[bi]=true;
            if(bp>0.5f && !used[si[bi]] && !used[sj[bi]]){
                used[si[bi]]=true; used[sj[bi]]=true;
                sel[b*256 + si[bi]*16 + sj[bi]] = 1.f;
            }
        }
    }
}

// ---------------- bf16 MFMA GEMM: Gx = A @ Bw^T + bias (out bf16) ----------------
__global__ __launch_bounds__(256) void k_gemm(const __hip_bfloat16* __restrict__ A, const __hip_bfloat16* __restrict__ Bw,
                                              const float* __restrict__ bias, __hip_bfloat16* __restrict__ C,
                                              int N, int KD){
    int nt = blockIdx.x, mt = blockIdx.y;
    __shared__ __hip_bfloat16 As[64][40];
    int tid = threadIdx.x, w = tid>>6, lane = tid&63, lo = lane&15, hi = lane>>4;
    f32x4 acc[4];
    #pragma unroll
    for(int s=0;s<4;s++) acc[s] = (f32x4){0.f,0.f,0.f,0.f};
    int r = tid>>2, kc = (tid&3)*8;
    for(int kk=0; kk<KD; kk+=32){
        __syncthreads();
        *(i32x4*)(&As[r][kc]) = *(const i32x4*)(A + ((size_t)(mt*64+r))*KD + kk + kc);
        __syncthreads();
        i32x4 bq = *(const i32x4*)(Bw + ((size_t)(nt*64 + w*16 + lo))*KD + kk + hi*8);
        asm volatile("s_nop 1" ::);
        #pragma unroll
        for(int s=0;s<4;s++){
            i32x4 a = *(const i32x4*)(&As[s*16+lo][hi*8]);
            asm volatile("v_mfma_f32_16x16x32_bf16 %0, %1, %2, %0" : "+v"(acc[s]) : "v"(a), "v"(bq));
        }
    }
    asm volatile("s_nop 7\n\ts_nop 7" ::);
    #pragma unroll
    for(int s=0;s<4;s++){
        int n = nt*64 + w*16 + lo;
        #pragma unroll
        for(int rr=0;rr<4;rr++){
            int m = mt*64 + s*16 + hi*4 + rr;
            C[(size_t)m*N + n] = __float2bfloat16(acc[s][rr] + bias[n]);
        }
    }
}

// ---------------- LSTM recurrence ----------------
// One 512-thread WG per direction. Whh fp8 resident in AGPRs, K=128 f8f6f4 MFMA.
// pi_A = pi_B symmetry: A and B fragments are both contiguous 32B/lane chunks of
// the same k-range, so the instruction's internal k-permutation cancels.
// One barrier per step; acc redistribution is wave-private (gate tiles chosen so
// all 4 gates of h-index p = w*32+s*16+lo live in wave w).
__global__ __launch_bounds__(512, 2) void k_recur(const float* __restrict__ Whh,
                                                  const __hip_bfloat16* __restrict__ Gx,
                                                  __hip_bfloat16* __restrict__ Hout, int layer){
    const int dir = blockIdx.x;
    const int tid = threadIdx.x, w = tid>>6, lane = tid&63, lo = lane&15, hi = lane>>4;
    __shared__ unsigned char hb[2][16][256];     // h fp8, XOR-block-swizzled; rows 8..15 zero
    __shared__ float gaccw[8][8][4][32];         // [wave][batch][gate][p] wave-private
    __shared__ __hip_bfloat16 gxs[2][8][1032];   // [buf][batch][1024+pad]
    __shared__ float lds_pad[2100];              // total LDS > 80KB: 1 WG/CU
    if(Gx == nullptr) ((volatile float*)lds_pad)[0] = 1.f;

    for(int i=tid; i<2048; i+=512) ((int*)hb)[i] = 0;

    // preload Whh fp8 fragments -> AGPRs. tau = q*2+s covers gate j = q*256+w*32+s*16+lo
    i32x8 bf[8][2];
    const float* wbase = Whh + ((size_t)(layer*2 + dir)*1024)*256;
    #pragma unroll
    for(int q=0;q<4;q++){
        #pragma unroll
        for(int s=0;s<2;s++){
            int j = q*256 + w*32 + s*16 + lo;
            const float* wr = wbase + (size_t)j*256;
            #pragma unroll
            for(int c=0;c<2;c++){
                i32x8 v;
                #pragma unroll
                for(int u=0; u<8; ++u){
                    f32x4 wv = *(const f32x4*)(wr + c*128 + hi*32 + u*4);
                    int pk = __builtin_amdgcn_cvt_pk_fp8_f32(wv.x, wv.y, 0, false);
                    pk = __builtin_amdgcn_cvt_pk_fp8_f32(wv.z, wv.w, pk, true);
                    v[u] = pk;
                }
                bf[q*2+s][c] = v;
            }
        }
    }
    float cst[4] = {0.f, 0.f, 0.f, 0.f};
    const int eb  = lane>>3;        // epilogue batch
    const int ep0 = (lane&7)*4;     // epilogue h-start (within wave's 32)
    const int gp  = w*32 + ep0;     // global h index

    // prologue: stage Gx row for t=0
    {
        int t0 = dir ? (LSEQ-1) : 0;
        const __hip_bfloat16* src = Gx + (size_t)w*4194304 + (size_t)t0*2048 + dir*1024;
        GLDS(src + lane*8, &gxs[0][w][0]);
        GLDS(src + 512 + lane*8, &gxs[0][w][512]);
    }
    asm volatile("s_waitcnt vmcnt(0) lgkmcnt(0)" ::: "memory");
    __builtin_amdgcn_s_barrier();
    __builtin_amdgcn_sched_barrier(0);

    int cur = 0;
    for(int t=0; t<LSEQ; ++t){
        const int tt = dir ? (LSEQ-1-t) : t;
        const int nxt = cur^1;
        // A fragments from hb[cur] (swizzled blocks)
        i32x8 af[2];
        #pragma unroll
        for(int c=0;c<2;c++){
            const unsigned char* rb = &hb[cur][0][0] + lo*256 + c*128;
            i32x4 v0 = *(const i32x4*)(rb + ((((hi*2  ) ^ (lo&7)) & 7) << 4));
            i32x4 v1 = *(const i32x4*)(rb + ((((hi*2+1) ^ (lo&7)) & 7) << 4));
            af[c] = __builtin_shufflevector(v0, v1, 0,1,2,3,4,5,6,7);
        }
        // prefetch Gx for t+1
        {
            int tn_t = (t+1 < LSEQ) ? (t+1) : (LSEQ-1);
            int tn = dir ? (LSEQ-1-tn_t) : tn_t;
            const __hip_bfloat16* src = Gx + (size_t)w*4194304 + (size_t)tn*2048 + dir*1024;
            GLDS(src + lane*8, &gxs[nxt][w][0]);
            GLDS(src + 512 + lane*8, &gxs[nxt][w][512]);
        }
        // MFMA: 16x16x128 fp8, B from AGPR
        f32x4 acc[8];
        #pragma unroll
        for(int i=0;i<8;i++) acc[i] = (f32x4){0.f,0.f,0.f,0.f};
        asm volatile("s_nop 1" ::);
        #pragma unroll
        for(int c=0;c<2;c++){
            #pragma unroll
            for(int i=0;i<8;i++)
                asm volatile("v_mfma_f32_16x16x128_f8f6f4 %0, %1, %2, %0"
                             : "+v"(acc[i]) : "v"(af[c]), "a"(bf[i][c]));
        }
        asm volatile("s_nop 7\n\ts_nop 7\n\ts_nop 7" ::);
        // scatter acc -> wave-private gacc (C row = hi*4+reg = batch, col = gate)
        if(hi<2){
            #pragma unroll
            for(int q=0;q<4;q++){
                #pragma unroll
                for(int s=0;s<2;s++){
                    #pragma unroll
                    for(int rr=0;rr<4;rr++)
                        gaccw[w][hi*4+rr][q][s*16+lo] = acc[q*2+s][rr];
                }
            }
        }
        asm volatile("s_waitcnt lgkmcnt(0)" ::: "memory");
        __builtin_amdgcn_sched_barrier(0);
        // epilogue: all 512 lanes, 4 h each (batch eb, h gp..gp+3)
        {
            f32x4 gI = *(const f32x4*)&gaccw[w][eb][0][ep0];
            f32x4 gF = *(const f32x4*)&gaccw[w][eb][1][ep0];
            f32x4 gG = *(const f32x4*)&gaccw[w][eb][2][ep0];
            f32x4 gO = *(const f32x4*)&gaccw[w][eb][3][ep0];
            unsigned long long xI = *(const unsigned long long*)&gxs[cur][eb][      gp];
            unsigned long long xF = *(const unsigned long long*)&gxs[cur][eb][256 + gp];
            unsigned long long xG = *(const unsigned long long*)&gxs[cur][eb][512 + gp];
            unsigned long long xO = *(const unsigned long long*)&gxs[cur][eb][768 + gp];
            float hh[4];
            #pragma unroll
            for(int jj=0; jj<4; ++jj){
                int sh = jj*16;
                float gi = gI[jj] + bf16u(xI>>sh);
                float gf = gF[jj] + bf16u(xF>>sh);
                float gg = gG[jj] + bf16u(xG>>sh);
                float go = gO[jj] + bf16u(xO>>sh);
                float sf = rcp_(1.f + ex2_(gf * -1.44269504f));
                float ag = ex2_(clamp60(gg * 2.88539008f));
                float bi = ex2_(clamp60(gi * -1.44269504f));
                float it = (ag - 1.f) * rcp_((1.f + bi) * (ag + 1.f));
                float c  = sf*cst[jj] + it;
                cst[jj] = c;
                float ac = ex2_(clamp60(c * 2.88539008f));
                float bo = ex2_(clamp60(go * -1.44269504f));
                hh[jj] = (ac - 1.f) * rcp_((1.f + bo) * (ac + 1.f));
            }
            // h -> hb[nxt] (fp8, swizzled): kk = gp, row = eb
            int pk = __builtin_amdgcn_cvt_pk_fp8_f32(hh[0], hh[1], 0, false);
            pk = __builtin_amdgcn_cvt_pk_fp8_f32(hh[2], hh[3], pk, true);
            int cch = w>>2;
            int blk = ((2*w + (ep0>>4)) ^ eb) & 7;
            *(unsigned int*)(&hb[nxt][0][0] + eb*256 + (cch<<7) + (blk<<4) + (ep0&15)) = (unsigned)pk;
            // Hout bf16
            __hip_bfloat16 b0 = __float2bfloat16(hh[0]), b1 = __float2bfloat16(hh[1]);
            __hip_bfloat16 b2 = __float2bfloat16(hh[2]), b3 = __float2bfloat16(hh[3]);
            uint2 hv;
            hv.x = (unsigned)*(unsigned short*)&b0 | ((unsigned)*(unsigned short*)&b1 << 16);
            hv.y = (unsigned)*(unsigned short*)&b2 | ((unsigned)*(unsigned short*)&b3 << 16);
            *(uint2*)&Hout[((size_t)eb*LSEQ + tt)*512 + dir*256 + gp] = hv;
        }
        // publish: own GLDS (2 newest-1) landed + h ds_writes done, then barrier
        asm volatile("s_waitcnt vmcnt(1) lgkmcnt(0)" ::: "memory");
        __builtin_amdgcn_s_barrier();
        __builtin_amdgcn_sched_barrier(0);
        cur = nxt;
    }
}

// ---------------- ce = h + 0.4*opt*win + dsb*cm (bf16) ----------------
__global__ void k_ce(const float* __restrict__ hs, const __hip_bfloat16* __restrict__ opt,
                     const float* __restrict__ win, const float* __restrict__ cm,
                     const float* __restrict__ dsb, __hip_bfloat16* __restrict__ ce){
    size_t i = (size_t)blockIdx.x*blockDim.x + threadIdx.x;
    size_t base = i*4;
    if(base >= (size_t)NB*LSEQ*DDIM) return;
    int d = (int)(base & 511);
    size_t bt = base >> 9;
    float wv = win[bt]*0.4f, cv = cm[bt];
    f32x4 h = *(const f32x4*)(hs + base);
    unsigned long long uv = *(const unsigned long long*)(opt + base);
    float o0 = __uint_as_float((unsigned)(uv & 0xffffull) << 16);
    float o1 = __uint_as_float((unsigned)((uv>>16) & 0xffffull) << 16);
    float o2 = __uint_as_float((unsigned)((uv>>32) & 0xffffull) << 16);
    float o3 = __uint_as_float((unsigned)((uv>>48) & 0xffffull) << 16);
    f32x4 dv = *(const f32x4*)(dsb + d);
    ce[base+0] = __float2bfloat16(h.x + wv*o0 + dv.x*cv);
    ce[base+1] = __float2bfloat16(h.y + wv*o1 + dv.y*cv);
    ce[base+2] = __float2bfloat16(h.z + wv*o2 + dv.z*cv);
    ce[base+3] = __float2bfloat16(h.w + wv*o3 + dv.w*cv);
}

// ---------------- conv (11 taps, MFMA) + final fusion ----------------
__global__ __launch_bounds__(256) void k_conv(const __hip_bfloat16* __restrict__ ce, const __hip_bfloat16* __restrict__ wt,
                                              const float* __restrict__ convb, const float* __restrict__ hs,
                                              float* __restrict__ outp){
    int nt = blockIdx.x, mt = blockIdx.y, b = blockIdx.z;
    __shared__ __hip_bfloat16 S[74][520];
    int tid = threadIdx.x;
    for(int i=tid; i<74*64; i+=256){
        int rq = i>>6, kc = (i&63)*8;
        int tok = mt*64 - 5 + rq;
        i32x4 v = (i32x4){0,0,0,0};
        if(tok>=0 && tok<LSEQ) v = *(const i32x4*)(ce + ((size_t)b*LSEQ + tok)*512 + kc);
        *(i32x4*)(&S[rq][kc]) = v;
    }
    __syncthreads();
    int w = tid>>6, lane = tid&63, lo = lane&15, hi = lane>>4;
    f32x4 acc[4];
    #pragma unroll
    for(int s=0;s<4;s++) acc[s] = (f32x4){0.f,0.f,0.f,0.f};
    asm volatile("s_nop 1" ::);
    for(int tap=0; tap<11; ++tap){
        const __hip_bfloat16* wtp = wt + (size_t)tap*262144;
        for(int kk=0; kk<512; kk+=32){
            i32x4 a = *(const i32x4*)(&S[16*w + lo + tap][kk + hi*8]);
            #pragma unroll
            for(int s=0;s<4;s++){
                i32x4 bq = *(const i32x4*)(wtp + (size_t)(nt*64 + s*16 + lo)*512 + kk + hi*8);
                asm volatile("v_mfma_f32_16x16x32_bf16 %0, %1, %2, %0" : "+v"(acc[s]) : "v"(a), "v"(bq));
            }
        }
    }
    asm volatile("s_nop 7\n\ts_nop 7" ::);
    #pragma unroll
    for(int s=0;s<4;s++){
        int co = nt*64 + s*16 + lo;
        float cb = convb[co];
        #pragma unroll
        for(int rr=0; rr<4; ++rr){
            int row = hi*4 + rr;
            int tok = mt*64 + 16*w + row;
            size_t gi = ((size_t)b*LSEQ + tok)*512 + co;
            float h   = hs[gi];
            float cef = __bfloat162float(S[16*w + row + 5][co]);
            outp[gi] = 0.5f*h + 0.3f*cef + 0.2f*(acc[s][rr] + cb);
        }
    }
}

// ---------------- launch ----------------
extern "C" void kernel_launch(void* const* d_in, const int* in_sizes, int n_in,
                              void* d_out, int out_size, void* d_ws, size_t ws_size,
                              hipStream_t stream)
{
    (void)in_sizes; (void)n_in; (void)out_size; (void)ws_size;
    const float* hidden = (const float*)d_in[0];
    const int*   aa     = (const int*)d_in[1];
    const float* Wbil   = (const float*)d_in[2];
    const float* bbil   = (const float*)d_in[3];
    const float* w1     = (const float*)d_in[4];
    const float* b1     = (const float*)d_in[5];
    const float* w2     = (const float*)d_in[6];
    const float* b2     = (const float*)d_in[7];
    const float* Wih    = (const float*)d_in[8];
    const float* Whh    = (const float*)d_in[9];
    const float* bih    = (const float*)d_in[10];
    const float* bhh    = (const float*)d_in[11];
    const float* convw  = (const float*)d_in[12];
    const float* convb  = (const float*)d_in[13];
    const float* dsb    = (const float*)d_in[14];

    float* outp = (float*)d_out;
    float* prob = outp + (size_t)NB*LSEQ*DDIM;           // 8388608
    float* sel  = prob + NB*KC*KC;                       // +2048

    char* p = (char*)d_ws;
    auto alloc = [&](size_t bytes)->char*{ char* r = p; p += (bytes + 255) & ~(size_t)255; return r; };
    __hip_bfloat16* gx    = (__hip_bfloat16*)alloc((size_t)16384*2048*2);
    __hip_bfloat16* hbf   = (__hip_bfloat16*)alloc((size_t)NB*LSEQ*DDIM*2);
    __hip_bfloat16* wihbf = (__hip_bfloat16*)alloc((size_t)2*2048*512*2);
    float*          bias2 = (float*)        alloc((size_t)2*2048*4);
    __hip_bfloat16* out1  = (__hip_bfloat16*)alloc((size_t)NB*LSEQ*DDIM*2);
    __hip_bfloat16* out2  = (__hip_bfloat16*)alloc((size_t)NB*LSEQ*DDIM*2);
    __hip_bfloat16* cebf  = (__hip_bfloat16*)alloc((size_t)NB*LSEQ*DDIM*2);
    __hip_bfloat16* wtc   = (__hip_bfloat16*)alloc((size_t)11*512*512*2);
    float*          feats = (float*)        alloc((size_t)NB*KC*DDIM*4);
    float*          pf    = (float*)        alloc((size_t)NB*KC*KC*128*4);
    int*            pos   = (int*)          alloc((size_t)NB*KC*4);
    float*          cm    = (float*)        alloc((size_t)NB*LSEQ*4);
    float*          win   = (float*)        alloc((size_t)NB*LSEQ*4);

    // prep
    k_cast<<<(NB*LSEQ*DDIM+255)/256, 256, 0, stream>>>(hidden, hbf, NB*LSEQ*DDIM);
    k_cast<<<(2*2048*512+255)/256,   256, 0, stream>>>(Wih, wihbf, 2*2048*512);
    k_addb<<<(4096+255)/256,         256, 0, stream>>>(bih, bhh, bias2, 4096);
    k_convw<<<(512*512+255)/256,     256, 0, stream>>>(convw, wtc);

    // classifier path (fp32)
    k_poswin<<<NB, 256, 0, stream>>>(aa, pos, cm, win);
    k_gather<<<dim3(KC, NB), 128, 0, stream>>>(hidden, pos, feats);
    k_bilinear<<<dim3(128, NB), 256, 0, stream>>>(feats, Wbil, bbil, pf);
    k_cls<<<NB, 256, 0, stream>>>(pf, w1, b1, w2, b2, pos, prob);
    k_greedy<<<NB, 64, 0, stream>>>(prob, sel);

    // BiLSTM layer 1
    k_gemm<<<dim3(32, 256), 256, 0, stream>>>(hbf, wihbf, bias2, gx, 2048, 512);
    k_recur<<<2, 512, 0, stream>>>(Whh, gx, out1, 0);
    // BiLSTM layer 2
    k_gemm<<<dim3(32, 256), 256, 0, stream>>>(out1, wihbf + (size_t)2048*512, bias2 + 2048, gx, 2048, 512);
    k_recur<<<2, 512, 0, stream>>>(Whh, gx, out2, 1);

    // fusion
    k_ce<<<(NB*LSEQ*DDIM/4+255)/256, 256, 0, stream>>>(hidden, out2, win, cm, dsb, cebf);
    k_conv<<<dim3(8, 32, NB), 256, 0, stream>>>(cebf, wtc, convb, hidden, outp);
}

// Round 4
// 5350.830 us; speedup vs baseline: 3.4338x; 1.5133x over previous
//
#include <hip/hip_runtime.h>
#include <hip/hip_bf16.h>

typedef float  f32x4 __attribute__((ext_vector_type(4)));
typedef float  f32x2 __attribute__((ext_vector_type(2)));
typedef int    i32x4 __attribute__((ext_vector_type(4)));
typedef int    i32x8 __attribute__((ext_vector_type(8)));

#define NB   8
#define LSEQ 2048
#define DDIM 512
#define KC   16

__device__ __forceinline__ float rcp_(float x){ return __builtin_amdgcn_rcpf(x); }
__device__ __forceinline__ float ex2_(float x){ return __builtin_amdgcn_exp2f(x); }
__device__ __forceinline__ float clamp60(float x){ return fminf(fmaxf(x, -60.f), 60.f); }

#define GLDS(gp, lp) __builtin_amdgcn_global_load_lds(                      \
    (__attribute__((address_space(1))) const void*)(gp),                   \
    (__attribute__((address_space(3))) void*)(lp), 16, 0, 0)

// ---------------- prep kernels ----------------
__global__ void k_cast(const float* __restrict__ in, __hip_bfloat16* __restrict__ out, int n){
    int i = blockIdx.x*blockDim.x + threadIdx.x;
    if(i<n) out[i] = __float2bfloat16(in[i]);
}
__global__ void k_addb(const float* __restrict__ a, const float* __restrict__ b, float* __restrict__ o, int n){
    int i = blockIdx.x*blockDim.x + threadIdx.x;
    if(i<n) o[i] = a[i]+b[i];
}
// conv_w [co][ci][11] f32 -> wt [tap][co][ci] bf16
__global__ void k_convw(const float* __restrict__ w, __hip_bfloat16* __restrict__ wt){
    int idx = blockIdx.x*blockDim.x + threadIdx.x;
    if(idx < 512*512){
        #pragma unroll
        for(int tap=0; tap<11; ++tap)
            wt[(size_t)tap*262144 + idx] = __float2bfloat16(w[(size_t)idx*11 + tap]);
    }
}

// ---------------- positions / masks ----------------
__global__ void k_poswin(const int* __restrict__ aa, int* __restrict__ pos,
                         float* __restrict__ cm, float* __restrict__ win){
    int b = blockIdx.x;
    __shared__ unsigned char fl[LSEQ];
    for(int t=threadIdx.x; t<LSEQ; t+=blockDim.x) fl[t] = (aa[b*LSEQ+t]==4) ? 1 : 0;
    __syncthreads();
    if(threadIdx.x==0){
        int c=0;
        for(int t=0; t<LSEQ && c<KC; ++t) if(fl[t]) pos[b*KC + c++] = t;
        for(; c<KC; ++c) pos[b*KC+c]=0;
    }
    for(int t=threadIdx.x; t<LSEQ; t+=blockDim.x){
        cm[b*LSEQ+t] = fl[t] ? 1.f : 0.f;
        int lo = t-5 < 0 ? 0 : t-5;
        int hi = t+5 > LSEQ-1 ? LSEQ-1 : t+5;
        float wv = 0.f;
        for(int u=lo; u<=hi; ++u) if(fl[u]) wv = 1.f;
        win[b*LSEQ+t] = wv;
    }
}

__global__ void k_gather(const float* __restrict__ hs, const int* __restrict__ pos, float* __restrict__ feats){
    int k = blockIdx.x, b = blockIdx.y;
    int p = pos[b*KC+k];
    const f32x4* src = (const f32x4*)(hs + ((size_t)b*LSEQ + p)*DDIM);
    f32x4* dst = (f32x4*)(feats + ((size_t)b*KC + k)*DDIM);
    dst[threadIdx.x] = src[threadIdx.x];   // 128 threads * 4 floats
}

// ---------------- bilinear pf[b,k,m,c] (fp32) ----------------
__global__ __launch_bounds__(256) void k_bilinear(const float* __restrict__ feats, const float* __restrict__ Wb,
                                                  const float* __restrict__ bb, float* __restrict__ pf){
    int c = blockIdx.x, b = blockIdx.y;
    __shared__ float fl[16][516];
    __shared__ float tl[16][516];
    const float* fbase = feats + (size_t)b*16*512;
    for(int i=threadIdx.x; i<2048; i+=256){
        int k = i>>7, d = (i&127)*4;
        f32x4 v = *(const f32x4*)(fbase + k*512 + d);
        fl[k][d]=v.x; fl[k][d+1]=v.y; fl[k][d+2]=v.z; fl[k][d+3]=v.w;
    }
    __syncthreads();
    int e0 = threadIdx.x*2;
    float acc0[16], acc1[16];
    #pragma unroll
    for(int k=0;k<16;k++){ acc0[k]=0.f; acc1[k]=0.f; }
    const float* wc = Wb + (size_t)c*512*512;
    for(int d=0; d<512; ++d){
        f32x2 wv = *(const f32x2*)(wc + (size_t)d*512 + e0);
        #pragma unroll
        for(int k=0;k<16;k++){ float f = fl[k][d]; acc0[k] += f*wv.x; acc1[k] += f*wv.y; }
    }
    #pragma unroll
    for(int k=0;k<16;k++){ tl[k][e0]=acc0[k]; tl[k][e0+1]=acc1[k]; }
    __syncthreads();
    int kq = threadIdx.x>>4, mq = threadIdx.x&15;
    const f32x4* tp = (const f32x4*)&tl[kq][0];
    const f32x4* fp = (const f32x4*)&fl[mq][0];
    float s = 0.f;
    #pragma unroll 8
    for(int e=0;e<128;e++){ f32x4 a=tp[e], v=fp[e]; s += a.x*v.x + a.y*v.y + a.z*v.z + a.w*v.w; }
    pf[(((size_t)b*16+kq)*16+mq)*128 + c] = s + bb[c];
}

// ---------------- classifier -> prob ----------------
__global__ __launch_bounds__(256) void k_cls(const float* __restrict__ pf, const float* __restrict__ w1,
                                             const float* __restrict__ b1, const float* __restrict__ w2,
                                             const float* __restrict__ b2, const int* __restrict__ pos,
                                             float* __restrict__ prob){
    int b = blockIdx.x;
    __shared__ float sw1[64][128];
    __shared__ float sw2[64], sb1[64];
    for(int i=threadIdx.x; i<8192; i+=256) sw1[i>>7][i&127] = w1[i];
    if(threadIdx.x<64){ sw2[threadIdx.x]=w2[threadIdx.x]; sb1[threadIdx.x]=b1[threadIdx.x]; }
    __syncthreads();
    int k = threadIdx.x>>4, m = threadIdx.x&15;
    const f32x4* pp = (const f32x4*)(pf + (((size_t)b*16+k)*16+m)*128);
    f32x4 pr[32];
    #pragma unroll
    for(int i=0;i<32;i++) pr[i] = pp[i];
    float lg = b2[0];
    for(int n=0;n<64;n++){
        const f32x4* wr = (const f32x4*)&sw1[n][0];
        float a = sb1[n];
        #pragma unroll
        for(int i=0;i<32;i++){ f32x4 wv = wr[i]; a += pr[i].x*wv.x + pr[i].y*wv.y + pr[i].z*wv.z + pr[i].w*wv.w; }
        a = fmaxf(a, 0.f);
        lg += a*sw2[n];
    }
    float p = rcp_(1.f + ex2_(lg * -1.44269504f));
    int dk = pos[b*16+k]-pos[b*16+m]; if(dk<0) dk=-dk;
    if(dk<2) p *= 0.1f;
    prob[b*256 + k*16 + m] = p;
}

// ---------------- greedy matching -> sel ----------------
__global__ void k_greedy(const float* __restrict__ prob, float* __restrict__ sel){
    int b = blockIdx.x;
    __shared__ float sp[120];
    __shared__ unsigned char si[120], sj[120];
    if(threadIdx.x==0){
        int idx=0;
        for(int i=0;i<16;i++) for(int j=i+1;j<16;j++){ si[idx]=(unsigned char)i; sj[idx]=(unsigned char)j; idx++; }
    }
    for(int i=threadIdx.x;i<256;i+=blockDim.x) sel[b*256+i]=0.f;
    __syncthreads();
    for(int q=threadIdx.x;q<120;q+=blockDim.x) sp[q] = prob[b*256 + si[q]*16 + sj[q]];
    __syncthreads();
    if(threadIdx.x==0){
        bool done[120]; bool used[16];
        for(int i=0;i<120;i++) done[i]=false;
        for(int i=0;i<16;i++)  used[i]=false;
        for(int it=0; it<120; ++it){
            int bi=-1; float bp=-1e30f;
            for(int q=0;q<120;q++) if(!done[q] && sp[q]>bp){ bp=sp[q]; bi=q; }
            done[bi]=true;
            if(bp>0.5f && !used[si[bi]] && !used[sj[bi]]){
                used[si[bi]]=true; used[sj[bi]]=true;
                sel[b*256 + si[bi]*16 + sj[bi]] = 1.f;
            }
        }
    }
}

// ---------------- bf16 MFMA GEMM: Gx = A @ Bw^T + bias (out bf16) ----------------
__global__ __launch_bounds__(256) void k_gemm(const __hip_bfloat16* __restrict__ A, const __hip_bfloat16* __restrict__ Bw,
                                              const float* __restrict__ bias, __hip_bfloat16* __restrict__ C,
                                              int N, int KD){
    int nt = blockIdx.x, mt = blockIdx.y;
    __shared__ __hip_bfloat16 As[64][40];
    int tid = threadIdx.x, w = tid>>6, lane = tid&63, lo = lane&15, hi = lane>>4;
    f32x4 acc[4];
    #pragma unroll
    for(int s=0;s<4;s++) acc[s] = (f32x4){0.f,0.f,0.f,0.f};
    int r = tid>>2, kc = (tid&3)*8;
    for(int kk=0; kk<KD; kk+=32){
        __syncthreads();
        *(i32x4*)(&As[r][kc]) = *(const i32x4*)(A + ((size_t)(mt*64+r))*KD + kk + kc);
        __syncthreads();
        i32x4 bq = *(const i32x4*)(Bw + ((size_t)(nt*64 + w*16 + lo))*KD + kk + hi*8);
        asm volatile("s_nop 1" ::);
        #pragma unroll
        for(int s=0;s<4;s++){
            i32x4 a = *(const i32x4*)(&As[s*16+lo][hi*8]);
            asm volatile("v_mfma_f32_16x16x32_bf16 %0, %1, %2, %0" : "+v"(acc[s]) : "v"(a), "v"(bq));
        }
    }
    asm volatile("s_nop 7\n\ts_nop 7" ::);
    #pragma unroll
    for(int s=0;s<4;s++){
        int n = nt*64 + w*16 + lo;
        #pragma unroll
        for(int rr=0;rr<4;rr++){
            int m = mt*64 + s*16 + hi*4 + rr;
            C[(size_t)m*N + n] = __float2bfloat16(acc[s][rr] + bias[n]);
        }
    }
}

// ---------------- LSTM recurrence ----------------
// Batch-split: one 512-thread WG per (batch, dir) -> 16 WGs. M=16 MFMA tile holds
// ONE batch broadcast to all rows, so the A-operand is a broadcast LDS read and
// every lane holds all 4 gates of its h-index in registers (no LDS redistribution).
// Whh fp8 in AGPRs, 16x16x128 f8f6f4 MFMA (pi_A = pi_B chunk symmetry).
// Gx staged via global_load_lds, double-buffered, vmcnt(1) keeps prefetch in flight.
__global__ __launch_bounds__(512, 2) void k_recur(const float* __restrict__ Whh,
                                                  const __hip_bfloat16* __restrict__ Gx,
                                                  __hip_bfloat16* __restrict__ Hout, int layer){
    const int bat = blockIdx.x;
    const int dir = blockIdx.y;
    const int tid = threadIdx.x, w = tid>>6, lane = tid&63, lo = lane&15, hi = lane>>4;
    __shared__ unsigned char hb[2][256];      // h state, fp8
    __shared__ __hip_bfloat16 gxs[2][1024];   // staged Gx row (4 gates x 256)
    __shared__ char lds_pad[81920];           // force 1 WG/CU
    if(Gx == nullptr) ((volatile char*)lds_pad)[0] = 1;

    for(int i=tid; i<128; i+=512) ((int*)hb)[i] = 0;

    // preload Whh fp8 fragments -> AGPRs. i = q*2+s covers gate j = q*256+w*32+s*16+lo
    i32x8 bf[8][2];
    const float* wbase = Whh + ((size_t)(layer*2 + dir)*1024)*256;
    #pragma unroll
    for(int q=0;q<4;q++){
        #pragma unroll
        for(int s=0;s<2;s++){
            int j = q*256 + w*32 + s*16 + lo;
            const float* wr = wbase + (size_t)j*256;
            #pragma unroll
            for(int c=0;c<2;c++){
                i32x8 v;
                #pragma unroll
                for(int u=0; u<8; ++u){
                    f32x4 wv = *(const f32x4*)(wr + c*128 + hi*32 + u*4);
                    int pk = __builtin_amdgcn_cvt_pk_fp8_f32(wv.x, wv.y, 0, false);
                    pk = __builtin_amdgcn_cvt_pk_fp8_f32(wv.z, wv.w, pk, true);
                    v[u] = pk;
                }
                bf[q*2+s][c] = v;
            }
        }
    }
    const int pm = w*32 + ((hi&1)<<4) + lo;   // this lane's h index (hi 2,3 redundant)
    float cst = 0.f;
    const __hip_bfloat16* gxbase = Gx + (size_t)bat*LSEQ*2048 + dir*1024;

    // prologue: stage Gx row for t=0
    {
        int t0 = dir ? (LSEQ-1) : 0;
        if(w < 2) GLDS(gxbase + (size_t)t0*2048 + w*512 + lane*8, &gxs[0][w*512]);
    }
    asm volatile("s_waitcnt vmcnt(0) lgkmcnt(0)" ::: "memory");
    __builtin_amdgcn_s_barrier();
    __builtin_amdgcn_sched_barrier(0);

    int cur = 0;
    for(int t=0; t<LSEQ; ++t){
        const int tt = dir ? (LSEQ-1-t) : t;
        const int nxt = cur^1;
        // prefetch Gx(t+1) (waves 0,1 only; clamped dummy at last step)
        {
            int tn_t = (t+1 < LSEQ) ? (t+1) : (LSEQ-1);
            int tn = dir ? (LSEQ-1-tn_t) : tn_t;
            if(w < 2) GLDS(gxbase + (size_t)tn*2048 + w*512 + lane*8, &gxs[nxt][w*512]);
        }
        // A fragments: broadcast h slice for this lane's k-group (conflict-free)
        i32x8 af[2];
        #pragma unroll
        for(int c=0;c<2;c++){
            i32x4 v0 = *(const i32x4*)(&hb[cur][c*128 + hi*32]);
            i32x4 v1 = *(const i32x4*)(&hb[cur][c*128 + hi*32 + 16]);
            af[c] = __builtin_shufflevector(v0, v1, 0,1,2,3,4,5,6,7);
        }
        // MFMA: 16x16x128 fp8, B from AGPR
        f32x4 acc[8];
        #pragma unroll
        for(int i=0;i<8;i++) acc[i] = (f32x4){0.f,0.f,0.f,0.f};
        asm volatile("s_nop 1" ::);
        #pragma unroll
        for(int c=0;c<2;c++){
            #pragma unroll
            for(int i=0;i<8;i++)
                asm volatile("v_mfma_f32_16x16x128_f8f6f4 %0, %1, %2, %0"
                             : "+v"(acc[i]) : "v"(af[c]), "a"(bf[i][c]));
        }
        asm volatile("s_nop 7\n\ts_nop 7\n\ts_nop 7" ::);
        // epilogue: all rows of C identical -> gates live in registers
        {
            float aI = (hi&1) ? acc[1][0] : acc[0][0];
            float aF = (hi&1) ? acc[3][0] : acc[2][0];
            float aG = (hi&1) ? acc[5][0] : acc[4][0];
            float aO = (hi&1) ? acc[7][0] : acc[6][0];
            float gi = aI + __bfloat162float(gxs[cur][      pm]);
            float gf = aF + __bfloat162float(gxs[cur][256 + pm]);
            float gg = aG + __bfloat162float(gxs[cur][512 + pm]);
            float go = aO + __bfloat162float(gxs[cur][768 + pm]);
            float sf = rcp_(1.f + ex2_(gf * -1.44269504f));
            float ag = ex2_(clamp60(gg * 2.88539008f));
            float bi = ex2_(clamp60(gi * -1.44269504f));
            float it = (ag - 1.f) * rcp_((1.f + bi) * (ag + 1.f));
            float c  = sf*cst + it;
            cst = c;
            float ac = ex2_(clamp60(c * 2.88539008f));
            float bo = ex2_(clamp60(go * -1.44269504f));
            float h  = (ac - 1.f) * rcp_((1.f + bo) * (ac + 1.f));
            if(hi < 2){
                int pk = __builtin_amdgcn_cvt_pk_fp8_f32(h, h, 0, false);
                hb[nxt][pm] = (unsigned char)(pk & 0xff);
                Hout[((size_t)bat*LSEQ + tt)*512 + dir*256 + pm] = __float2bfloat16(h);
            }
        }
        // drain own GLDS (t+1) but leave the Hout store in flight; publish hb
        asm volatile("s_waitcnt vmcnt(1) lgkmcnt(0)" ::: "memory");
        __builtin_amdgcn_s_barrier();
        __builtin_amdgcn_sched_barrier(0);
        cur = nxt;
    }
}

// ---------------- ce = h + 0.4*opt*win + dsb*cm (bf16) ----------------
__global__ void k_ce(const float* __restrict__ hs, const __hip_bfloat16* __restrict__ opt,
                     const float* __restrict__ win, const float* __restrict__ cm,
                     const float* __restrict__ dsb, __hip_bfloat16* __restrict__ ce){
    size_t i = (size_t)blockIdx.x*blockDim.x + threadIdx.x;
    size_t base = i*4;
    if(base >= (size_t)NB*LSEQ*DDIM) return;
    int d = (int)(base & 511);
    size_t bt = base >> 9;
    float wv = win[bt]*0.4f, cv = cm[bt];
    f32x4 h = *(const f32x4*)(hs + base);
    unsigned long long uv = *(const unsigned long long*)(opt + base);
    float o0 = __uint_as_float((unsigned)(uv & 0xffffull) << 16);
    float o1 = __uint_as_float((unsigned)((uv>>16) & 0xffffull) << 16);
    float o2 = __uint_as_float((unsigned)((uv>>32) & 0xffffull) << 16);
    float o3 = __uint_as_float((unsigned)((uv>>48) & 0xffffull) << 16);
    f32x4 dv = *(const f32x4*)(dsb + d);
    ce[base+0] = __float2bfloat16(h.x + wv*o0 + dv.x*cv);
    ce[base+1] = __float2bfloat16(h.y + wv*o1 + dv.y*cv);
    ce[base+2] = __float2bfloat16(h.z + wv*o2 + dv.z*cv);
    ce[base+3] = __float2bfloat16(h.w + wv*o3 + dv.w*cv);
}

// ---------------- conv (11 taps, MFMA) + final fusion ----------------
__global__ __launch_bounds__(256) void k_conv(const __hip_bfloat16* __restrict__ ce, const __hip_bfloat16* __restrict__ wt,
                                              const float* __restrict__ convb, const float* __restrict__ hs,
                                              float* __restrict__ outp){
    int nt = blockIdx.x, mt = blockIdx.y, b = blockIdx.z;
    __shared__ __hip_bfloat16 S[74][520];
    int tid = threadIdx.x;
    for(int i=tid; i<74*64; i+=256){
        int rq = i>>6, kc = (i&63)*8;
        int tok = mt*64 - 5 + rq;
        i32x4 v = (i32x4){0,0,0,0};
        if(tok>=0 && tok<LSEQ) v = *(const i32x4*)(ce + ((size_t)b*LSEQ + tok)*512 + kc);
        *(i32x4*)(&S[rq][kc]) = v;
    }
    __syncthreads();
    int w = tid>>6, lane = tid&63, lo = lane&15, hi = lane>>4;
    f32x4 acc[4];
    #pragma unroll
    for(int s=0;s<4;s++) acc[s] = (f32x4){0.f,0.f,0.f,0.f};
    asm volatile("s_nop 1" ::);
    for(int tap=0; tap<11; ++tap){
        const __hip_bfloat16* wtp = wt + (size_t)tap*262144;
        for(int kk=0; kk<512; kk+=32){
            i32x4 a = *(const i32x4*)(&S[16*w + lo + tap][kk + hi*8]);
            #pragma unroll
            for(int s=0;s<4;s++){
                i32x4 bq = *(const i32x4*)(wtp + (size_t)(nt*64 + s*16 + lo)*512 + kk + hi*8);
                asm volatile("v_mfma_f32_16x16x32_bf16 %0, %1, %2, %0" : "+v"(acc[s]) : "v"(a), "v"(bq));
            }
        }
    }
    asm volatile("s_nop 7\n\ts_nop 7" ::);
    #pragma unroll
    for(int s=0;s<4;s++){
        int co = nt*64 + s*16 + lo;
        float cb = convb[co];
        #pragma unroll
        for(int rr=0; rr<4; ++rr){
            int row = hi*4 + rr;
            int tok = mt*64 + 16*w + row;
            size_t gi = ((size_t)b*LSEQ + tok)*512 + co;
            float h   = hs[gi];
            float cef = __bfloat162float(S[16*w + row + 5][co]);
            outp[gi] = 0.5f*h + 0.3f*cef + 0.2f*(acc[s][rr] + cb);
        }
    }
}

// ---------------- launch ----------------
extern "C" void kernel_launch(void* const* d_in, const int* in_sizes, int n_in,
                              void* d_out, int out_size, void* d_ws, size_t ws_size,
                              hipStream_t stream)
{
    (void)in_sizes; (void)n_in; (void)out_size; (void)ws_size;
    const float* hidden = (const float*)d_in[0];
    const int*   aa     = (const int*)d_in[1];
    const float* Wbil   = (const float*)d_in[2];
    const float* bbil   = (const float*)d_in[3];
    const float* w1     = (const float*)d_in[4];
    const float* b1     = (const float*)d_in[5];
    const float* w2     = (const float*)d_in[6];
    const float* b2     = (const float*)d_in[7];
    const float* Wih    = (const float*)d_in[8];
    const float* Whh    = (const float*)d_in[9];
    const float* bih    = (const float*)d_in[10];
    const float* bhh    = (const float*)d_in[11];
    const float* convw  = (const float*)d_in[12];
    const float* convb  = (const float*)d_in[13];
    const float* dsb    = (const float*)d_in[14];

    float* outp = (float*)d_out;
    float* prob = outp + (size_t)NB*LSEQ*DDIM;           // 8388608
    float* sel  = prob + NB*KC*KC;                       // +2048

    char* p = (char*)d_ws;
    auto alloc = [&](size_t bytes)->char*{ char* r = p; p += (bytes + 255) & ~(size_t)255; return r; };
    __hip_bfloat16* gx    = (__hip_bfloat16*)alloc((size_t)16384*2048*2);
    __hip_bfloat16* hbf   = (__hip_bfloat16*)alloc((size_t)NB*LSEQ*DDIM*2);
    __hip_bfloat16* wihbf = (__hip_bfloat16*)alloc((size_t)2*2048*512*2);
    float*          bias2 = (float*)        alloc((size_t)2*2048*4);
    __hip_bfloat16* out1  = (__hip_bfloat16*)alloc((size_t)NB*LSEQ*DDIM*2);
    __hip_bfloat16* out2  = (__hip_bfloat16*)alloc((size_t)NB*LSEQ*DDIM*2);
    __hip_bfloat16* cebf  = (__hip_bfloat16*)alloc((size_t)NB*LSEQ*DDIM*2);
    __hip_bfloat16* wtc   = (__hip_bfloat16*)alloc((size_t)11*512*512*2);
    float*          feats = (float*)        alloc((size_t)NB*KC*DDIM*4);
    float*          pf    = (float*)        alloc((size_t)NB*KC*KC*128*4);
    int*            pos   = (int*)          alloc((size_t)NB*KC*4);
    float*          cm    = (float*)        alloc((size_t)NB*LSEQ*4);
    float*          win   = (float*)        alloc((size_t)NB*LSEQ*4);

    // prep
    k_cast<<<(NB*LSEQ*DDIM+255)/256, 256, 0, stream>>>(hidden, hbf, NB*LSEQ*DDIM);
    k_cast<<<(2*2048*512+255)/256,   256, 0, stream>>>(Wih, wihbf, 2*2048*512);
    k_addb<<<(4096+255)/256,         256, 0, stream>>>(bih, bhh, bias2, 4096);
    k_convw<<<(512*512+255)/256,     256, 0, stream>>>(convw, wtc);

    // classifier path (fp32)
    k_poswin<<<NB, 256, 0, stream>>>(aa, pos, cm, win);
    k_gather<<<dim3(KC, NB), 128, 0, stream>>>(hidden, pos, feats);
    k_bilinear<<<dim3(128, NB), 256, 0, stream>>>(feats, Wbil, bbil, pf);
    k_cls<<<NB, 256, 0, stream>>>(pf, w1, b1, w2, b2, pos, prob);
    k_greedy<<<NB, 64, 0, stream>>>(prob, sel);

    // BiLSTM layer 1
    k_gemm<<<dim3(32, 256), 256, 0, stream>>>(hbf, wihbf, bias2, gx, 2048, 512);
    k_recur<<<dim3(NB, 2), 512, 0, stream>>>(Whh, gx, out1, 0);
    // BiLSTM layer 2
    k_gemm<<<dim3(32, 256), 256, 0, stream>>>(out1, wihbf + (size_t)2048*512, bias2 + 2048, gx, 2048, 512);
    k_recur<<<dim3(NB, 2), 512, 0, stream>>>(Whh, gx, out2, 1);

    // fusion
    k_ce<<<(NB*LSEQ*DDIM/4+255)/256, 256, 0, stream>>>(hidden, out2, win, cm, dsb, cebf);
    k_conv<<<dim3(8, 32, NB), 256, 0, stream>>>(cebf, wtc, convb, hidden, outp);
}

// Round 5
// 4061.543 us; speedup vs baseline: 4.5238x; 1.3174x over previous
//
#include <hip/hip_runtime.h>
#include <hip/hip_bf16.h>

typedef float  f32x4 __attribute__((ext_vector_type(4)));
typedef float  f32x2 __attribute__((ext_vector_type(2)));
typedef int    i32x4 __attribute__((ext_vector_type(4)));
typedef int    i32x8 __attribute__((ext_vector_type(8)));

#define NB   8
#define LSEQ 2048
#define DDIM 512
#define KC   16

__device__ __forceinline__ float rcp_(float x){ return __builtin_amdgcn_rcpf(x); }
__device__ __forceinline__ float ex2_(float x){ return __builtin_amdgcn_exp2f(x); }
__device__ __forceinline__ float clamp60(float x){ return fminf(fmaxf(x, -60.f), 60.f); }
__device__ __forceinline__ unsigned pk2(float a, float b){
    __hip_bfloat16 x=__float2bfloat16(a), y=__float2bfloat16(b);
    return (unsigned)*(unsigned short*)&x | ((unsigned)*(unsigned short*)&y<<16);
}

#define GLDS(gp, lp) __builtin_amdgcn_global_load_lds(                      \
    (__attribute__((address_space(1))) const void*)(gp),                   \
    (__attribute__((address_space(3))) void*)(lp), 16, 0, 0)

// ================= prep: casts + bias + convw + poswin =================
__global__ __launch_bounds__(256) void k_prep(const float* __restrict__ hidden, __hip_bfloat16* __restrict__ hbf,
                                              const float* __restrict__ Wih, __hip_bfloat16* __restrict__ wihbf,
                                              const float* __restrict__ bih, const float* __restrict__ bhh,
                                              float* __restrict__ bias2,
                                              const float* __restrict__ convw, __hip_bfloat16* __restrict__ wtc,
                                              const int* __restrict__ aa, int* __restrict__ pos,
                                              float* __restrict__ cm, float* __restrict__ win){
    int bid = blockIdx.x, tid = threadIdx.x;
    if(bid < 4096){                                  // cast hidden -> bf16 (x8)
        size_t i = (size_t)bid*256 + tid;
        const f32x4* s = (const f32x4*)(hidden + i*8);
        f32x4 v0 = s[0], v1 = s[1];
        i32x4 o; o.x = pk2(v0.x,v0.y); o.y = pk2(v0.z,v0.w);
                 o.z = pk2(v1.x,v1.y); o.w = pk2(v1.z,v1.w);
        ((i32x4*)hbf)[i] = o;
    } else if(bid < 5120){                           // cast Wih -> bf16 (x8)
        size_t i = (size_t)(bid-4096)*256 + tid;
        const f32x4* s = (const f32x4*)(Wih + i*8);
        f32x4 v0 = s[0], v1 = s[1];
        i32x4 o; o.x = pk2(v0.x,v0.y); o.y = pk2(v0.z,v0.w);
                 o.z = pk2(v1.x,v1.y); o.w = pk2(v1.z,v1.w);
        ((i32x4*)wihbf)[i] = o;
    } else if(bid < 5136){                           // bias2 = bih + bhh
        int i = (bid-5120)*256 + tid;
        bias2[i] = bih[i] + bhh[i];
    } else if(bid < 6160){                           // conv_w transpose -> wt[tap][co][ci]
        int idx = (bid-5136)*256 + tid;
        #pragma unroll
        for(int tap=0; tap<11; ++tap)
            wtc[(size_t)tap*262144 + idx] = __float2bfloat16(convw[(size_t)idx*11 + tap]);
    } else {                                          // poswin
        int b = bid - 6160;
        __shared__ unsigned char fl[LSEQ];
        for(int t=tid; t<LSEQ; t+=256) fl[t] = (aa[b*LSEQ+t]==4) ? 1 : 0;
        __syncthreads();
        if(tid==0){
            int c=0;
            for(int t=0; t<LSEQ && c<KC; ++t) if(fl[t]) pos[b*KC + c++] = t;
            for(; c<KC; ++c) pos[b*KC+c]=0;
        }
        for(int t=tid; t<LSEQ; t+=256){
            cm[b*LSEQ+t] = fl[t] ? 1.f : 0.f;
            int lo = t-5 < 0 ? 0 : t-5;
            int hi = t+5 > LSEQ-1 ? LSEQ-1 : t+5;
            float wv = 0.f;
            for(int u=lo; u<=hi; ++u) if(fl[u]) wv = 1.f;
            win[b*LSEQ+t] = wv;
        }
    }
}

// ================= bf16 MFMA GEMM 128x128 (m97-style, global_load_lds) =================
// C[m][n] = A[m][:] . Bw[n][:] + bias[n], bf16 out. K-chunk order identical to prior rounds.
__global__ __launch_bounds__(256) void k_gemm(const __hip_bfloat16* __restrict__ A, const __hip_bfloat16* __restrict__ Bw,
                                              const float* __restrict__ bias, __hip_bfloat16* __restrict__ C,
                                              int N, int KD){
    int nt = blockIdx.x, mt = blockIdx.y;
    __shared__ __hip_bfloat16 As[128][32];
    __shared__ __hip_bfloat16 Bs[128][32];
    int tid = threadIdx.x, w = tid>>6, lane = tid&63, lo = lane&15, hi = lane>>4;
    int wm = w>>1, wn = w&1;
    f32x4 acc[4][4];
    #pragma unroll
    for(int s=0;s<4;s++){
        #pragma unroll
        for(int t2=0;t2<4;t2++) acc[s][t2] = (f32x4){0.f,0.f,0.f,0.f};
    }
    int lr = lane>>2, lc = (lane&3)*8;
    const __hip_bfloat16* Ab = A  + (size_t)(mt*128)*KD;
    const __hip_bfloat16* Bb = Bw + (size_t)(nt*128)*KD;
    for(int kk=0; kk<KD; kk+=32){
        __builtin_amdgcn_s_barrier();
        GLDS(Ab + (size_t)(w*32    + lr)*KD + kk + lc, &As[w*32   ][0]);
        GLDS(Ab + (size_t)(w*32+16 + lr)*KD + kk + lc, &As[w*32+16][0]);
        GLDS(Bb + (size_t)(w*32    + lr)*KD + kk + lc, &Bs[w*32   ][0]);
        GLDS(Bb + (size_t)(w*32+16 + lr)*KD + kk + lc, &Bs[w*32+16][0]);
        asm volatile("s_waitcnt vmcnt(0)" ::: "memory");
        __builtin_amdgcn_s_barrier();
        i32x4 av[4], bv[4];
        #pragma unroll
        for(int s=0;s<4;s++) av[s] = *(const i32x4*)(&As[wm*64+s*16+lo][hi*8]);
        #pragma unroll
        for(int t2=0;t2<4;t2++) bv[t2] = *(const i32x4*)(&Bs[wn*64+t2*16+lo][hi*8]);
        asm volatile("s_nop 1" ::);
        #pragma unroll
        for(int s=0;s<4;s++){
            #pragma unroll
            for(int t2=0;t2<4;t2++)
                asm volatile("v_mfma_f32_16x16x32_bf16 %0, %1, %2, %0" : "+v"(acc[s][t2]) : "v"(av[s]), "v"(bv[t2]));
        }
    }
    asm volatile("s_nop 7\n\ts_nop 7" ::);
    #pragma unroll
    for(int t2=0;t2<4;t2++){
        int n = nt*128 + wn*64 + t2*16 + lo;
        float bn = bias[n];
        #pragma unroll
        for(int s=0;s<4;s++){
            #pragma unroll
            for(int rr=0;rr<4;rr++){
                int m = mt*128 + wm*64 + s*16 + hi*4 + rr;
                C[(size_t)m*N + n] = __float2bfloat16(acc[s][t2][rr] + bn);
            }
        }
    }
}

// ================= LSTM recurrence body (per-(batch,dir) WG, 3-deep Gx prefetch) =================
__device__ __forceinline__ void recur_body(char* smem, const float* __restrict__ Whh,
        const __hip_bfloat16* __restrict__ Gx, __hip_bfloat16* __restrict__ Hout,
        int layer, int bat, int dir){
    unsigned char (*hb)[256]   = (unsigned char(*)[256])smem;          // 2 x 256   (h fp8)
    __hip_bfloat16 (*gxs)[1024] = (__hip_bfloat16(*)[1024])(smem+512); // 3 x 2KB ring
    const int tid = threadIdx.x, w = tid>>6, lane = tid&63, lo = lane&15, hi = lane>>4;
    for(int i=tid; i<128; i+=512) ((int*)smem)[i] = 0;

    // Whh fp8 fragments -> AGPR. i = q*2+s covers gate j = q*256 + w*32 + s*16 + lo
    i32x8 bf[8][2];
    const float* wbase = Whh + ((size_t)(layer*2 + dir)*1024)*256;
    #pragma unroll
    for(int q=0;q<4;q++){
        #pragma unroll
        for(int s=0;s<2;s++){
            int j = q*256 + w*32 + s*16 + lo;
            const float* wr = wbase + (size_t)j*256;
            #pragma unroll
            for(int c=0;c<2;c++){
                i32x8 v;
                #pragma unroll
                for(int u=0; u<8; ++u){
                    f32x4 wv = *(const f32x4*)(wr + c*128 + hi*32 + u*4);
                    int pk = __builtin_amdgcn_cvt_pk_fp8_f32(wv.x, wv.y, 0, false);
                    pk = __builtin_amdgcn_cvt_pk_fp8_f32(wv.z, wv.w, pk, true);
                    v[u] = pk;
                }
                bf[q*2+s][c] = v;
            }
        }
    }
    const int pm = w*32 + ((hi&1)<<4) + lo;
    float cst = 0.f;
    const __hip_bfloat16* gxbase = Gx + (size_t)bat*LSEQ*2048 + dir*1024;

    {   // prologue: stage t=0,1
        int tok0 = dir ? (LSEQ-1) : 0;
        int tok1 = dir ? (LSEQ-2) : 1;
        if(w < 2){
            GLDS(gxbase + (size_t)tok0*2048 + w*512 + lane*8, &gxs[0][w*512]);
            GLDS(gxbase + (size_t)tok1*2048 + w*512 + lane*8, &gxs[1][w*512]);
        }
    }
    asm volatile("s_waitcnt vmcnt(1) lgkmcnt(0)" ::: "memory");
    __builtin_amdgcn_s_barrier();
    __builtin_amdgcn_sched_barrier(0);

    int cur = 0;
    for(int t=0; t<LSEQ; ++t){
        const int tt = dir ? (LSEQ-1-t) : t;
        const int hcur = t&1, hnxt = hcur^1;
        int nx2 = cur+2; if(nx2>=3) nx2-=3;
        {   // prefetch t+2
            int tp = (t+2 < LSEQ) ? (t+2) : (LSEQ-1);
            int tok = dir ? (LSEQ-1-tp) : tp;
            if(w < 2) GLDS(gxbase + (size_t)tok*2048 + w*512 + lane*8, &gxs[nx2][w*512]);
        }
        // A: broadcast h (fp8) slice for this lane's k-group
        i32x8 af[2];
        #pragma unroll
        for(int c=0;c<2;c++){
            i32x4 v0 = *(const i32x4*)(&hb[hcur][c*128 + hi*32]);
            i32x4 v1 = *(const i32x4*)(&hb[hcur][c*128 + hi*32 + 16]);
            af[c] = __builtin_shufflevector(v0, v1, 0,1,2,3,4,5,6,7);
        }
        f32x4 acc[8];
        #pragma unroll
        for(int i=0;i<8;i++) acc[i] = (f32x4){0.f,0.f,0.f,0.f};
        asm volatile("s_nop 1" ::);
        #pragma unroll
        for(int c=0;c<2;c++){
            #pragma unroll
            for(int i=0;i<8;i++)
                asm volatile("v_mfma_f32_16x16x128_f8f6f4 %0, %1, %2, %0"
                             : "+v"(acc[i]) : "v"(af[c]), "a"(bf[i][c]));
        }
        asm volatile("s_nop 7\n\ts_nop 7\n\ts_nop 7" ::);
        {   // epilogue (gates live in registers)
            float aI = (hi&1) ? acc[1][0] : acc[0][0];
            float aF = (hi&1) ? acc[3][0] : acc[2][0];
            float aG = (hi&1) ? acc[5][0] : acc[4][0];
            float aO = (hi&1) ? acc[7][0] : acc[6][0];
            float gi = aI + __bfloat162float(gxs[cur][      pm]);
            float gf = aF + __bfloat162float(gxs[cur][256 + pm]);
            float gg = aG + __bfloat162float(gxs[cur][512 + pm]);
            float go = aO + __bfloat162float(gxs[cur][768 + pm]);
            float sf = rcp_(1.f + ex2_(gf * -1.44269504f));
            float ag = ex2_(clamp60(gg * 2.88539008f));
            float bi = ex2_(clamp60(gi * -1.44269504f));
            float it = (ag - 1.f) * rcp_((1.f + bi) * (ag + 1.f));
            float c  = sf*cst + it;
            cst = c;
            float ac = ex2_(clamp60(c * 2.88539008f));
            float bo = ex2_(clamp60(go * -1.44269504f));
            float h  = (ac - 1.f) * rcp_((1.f + bo) * (ac + 1.f));
            if(hi < 2){
                int pk = __builtin_amdgcn_cvt_pk_fp8_f32(h, h, 0, false);
                hb[hnxt][pm] = (unsigned char)(pk & 0xff);
                Hout[((size_t)bat*LSEQ + tt)*512 + dir*256 + pm] = __float2bfloat16(h);
            }
        }
        // drain so that G(t+1) has landed (2 newest = {G(t+2), store(t)}); publish hb
        asm volatile("s_waitcnt vmcnt(2) lgkmcnt(0)" ::: "memory");
        __builtin_amdgcn_s_barrier();
        __builtin_amdgcn_sched_barrier(0);
        cur = (cur+1 == 3) ? 0 : cur+1;
    }
}

// ================= bilinear body (guest blocks of fused1) =================
__device__ __forceinline__ void bilinear_body(char* smem, const float* __restrict__ hidden,
        const int* __restrict__ pos, const float* __restrict__ Wb, const float* __restrict__ bb,
        float* __restrict__ pf, int idx){
    int c = idx & 127, b = idx >> 7;
    float (*fl)[516] = (float(*)[516])smem;
    float (*tl)[516] = (float(*)[516])(smem + 33024);
    int tid = threadIdx.x;
    for(int i=tid; i<2048; i+=512){
        int k = i>>7, d = (i&127)*4;
        int p = pos[b*KC + k];
        f32x4 v = *(const f32x4*)(hidden + ((size_t)b*LSEQ + p)*DDIM + d);
        fl[k][d]=v.x; fl[k][d+1]=v.y; fl[k][d+2]=v.z; fl[k][d+3]=v.w;
    }
    __syncthreads();
    int e = tid;                      // one column per thread (512 threads)
    float acc[16];
    #pragma unroll
    for(int k=0;k<16;k++) acc[k]=0.f;
    const float* wc = Wb + (size_t)c*512*512;
    for(int d=0; d<512; ++d){
        float wv = wc[(size_t)d*512 + e];
        #pragma unroll
        for(int k=0;k<16;k++) acc[k] += fl[k][d]*wv;
    }
    #pragma unroll
    for(int k=0;k<16;k++) tl[k][e] = acc[k];
    __syncthreads();
    if(tid < 256){
        int kq = tid>>4, mq = tid&15;
        const f32x4* tp = (const f32x4*)&tl[kq][0];
        const f32x4* fp = (const f32x4*)&fl[mq][0];
        float s = 0.f;
        #pragma unroll 8
        for(int e2=0;e2<128;e2++){ f32x4 a=tp[e2], v=fp[e2]; s += a.x*v.x + a.y*v.y + a.z*v.z + a.w*v.w; }
        pf[(((size_t)b*16+kq)*16+mq)*128 + c] = s + bb[c];
    }
}

// ================= cls + greedy body (guest blocks of fused2) =================
__device__ __forceinline__ void clsgreedy_body(char* smem, const float* __restrict__ pf,
        const float* __restrict__ w1, const float* __restrict__ b1,
        const float* __restrict__ w2, const float* __restrict__ b2,
        const int* __restrict__ pos, float* __restrict__ prob, float* __restrict__ sel, int b){
    float (*sw1)[128] = (float(*)[128])smem;
    float* sw2 = (float*)(smem + 32768);
    float* sb1 = sw2 + 64;
    float* sp  = sb1 + 64;
    unsigned char* si = (unsigned char*)(sp + 120);
    unsigned char* sj = si + 120;
    int tid = threadIdx.x;
    for(int i=tid; i<8192; i+=512) sw1[i>>7][i&127] = w1[i];
    if(tid<64){ sw2[tid]=w2[tid]; sb1[tid]=b1[tid]; }
    if(tid==0){
        int idx=0;
        for(int i=0;i<16;i++) for(int j=i+1;j<16;j++){ si[idx]=(unsigned char)i; sj[idx]=(unsigned char)j; idx++; }
    }
    if(tid<256) sel[b*256+tid] = 0.f;
    __syncthreads();
    if(tid < 256){
        int k = tid>>4, m = tid&15;
        const f32x4* pp = (const f32x4*)(pf + (((size_t)b*16+k)*16+m)*128);
        f32x4 pr[32];
        #pragma unroll
        for(int i=0;i<32;i++) pr[i] = pp[i];
        float lg = b2[0];
        for(int n=0;n<64;n++){
            const f32x4* wr = (const f32x4*)&sw1[n][0];
            float a = sb1[n];
            #pragma unroll
            for(int i=0;i<32;i++){ f32x4 wv = wr[i]; a += pr[i].x*wv.x + pr[i].y*wv.y + pr[i].z*wv.z + pr[i].w*wv.w; }
            a = fmaxf(a, 0.f);
            lg += a*sw2[n];
        }
        float p = rcp_(1.f + ex2_(lg * -1.44269504f));
        int dk = pos[b*16+k]-pos[b*16+m]; if(dk<0) dk=-dk;
        if(dk<2) p *= 0.1f;
        prob[b*256 + k*16 + m] = p;
        if(k < m) sp[k*(31-k)/2 + (m-k-1)] = p;
    }
    __syncthreads();
    if(tid==0){
        bool done[120]; bool used[16];
        for(int i=0;i<120;i++) done[i]=false;
        for(int i=0;i<16;i++)  used[i]=false;
        for(int it=0; it<120; ++it){
            int bi=-1; float bp=-1e30f;
            for(int q=0;q<120;q++) if(!done[q] && sp[q]>bp){ bp=sp[q]; bi=q; }
            done[bi]=true;
            if(bp>0.5f && !used[si[bi]] && !used[sj[bi]]){
                used[si[bi]]=true; used[sj[bi]]=true;
                sel[b*256 + si[bi]*16 + sj[bi]] = 1.f;
            }
        }
    }
}

// ================= fused launches =================
__global__ __launch_bounds__(512) void k_fused1(const float* __restrict__ Whh, const __hip_bfloat16* __restrict__ Gx,
        __hip_bfloat16* __restrict__ Hout,
        const float* __restrict__ hidden, const int* __restrict__ pos,
        const float* __restrict__ Wbil, const float* __restrict__ bbil, float* __restrict__ pf){
    __shared__ __attribute__((aligned(16))) char smem[98304];
    if(blockIdx.x < 16){
        recur_body(smem, Whh, Gx, Hout, 0, blockIdx.x>>1, blockIdx.x&1);
    } else {
        bilinear_body(smem, hidden, pos, Wbil, bbil, pf, blockIdx.x - 16);
    }
}

__global__ __launch_bounds__(512) void k_fused2(const float* __restrict__ Whh, const __hip_bfloat16* __restrict__ Gx,
        __hip_bfloat16* __restrict__ Hout,
        const float* __restrict__ pf, const float* __restrict__ w1, const float* __restrict__ b1,
        const float* __restrict__ w2, const float* __restrict__ b2, const int* __restrict__ pos,
        float* __restrict__ prob, float* __restrict__ sel){
    __shared__ __attribute__((aligned(16))) char smem[98304];
    if(blockIdx.x < 16){
        recur_body(smem, Whh, Gx, Hout, 1, blockIdx.x>>1, blockIdx.x&1);
    } else {
        clsgreedy_body(smem, pf, w1, b1, w2, b2, pos, prob, sel, blockIdx.x - 16);
    }
}

// ================= conv (ce computed in staging) + final fusion =================
__global__ __launch_bounds__(256) void k_convce(const float* __restrict__ hs, const __hip_bfloat16* __restrict__ opt,
        const float* __restrict__ win, const float* __restrict__ cm, const float* __restrict__ dsb,
        const __hip_bfloat16* __restrict__ wt, const float* __restrict__ convb, float* __restrict__ outp){
    int mt = blockIdx.x & 31, b = blockIdx.x >> 5;
    __shared__ __hip_bfloat16 S[74][520];
    int tid = threadIdx.x;
    for(int i=tid; i<74*64; i+=256){
        int rq = i>>6, cc = (i&63)*8;
        int tok = mt*64 - 5 + rq;
        i32x4 o = (i32x4){0,0,0,0};
        if(tok>=0 && tok<LSEQ){
            size_t base = ((size_t)b*LSEQ + tok)*512 + cc;
            float wv = win[b*LSEQ+tok]*0.4f, cv = cm[b*LSEQ+tok];
            f32x4 h0 = *(const f32x4*)(hs + base);
            f32x4 h1 = *(const f32x4*)(hs + base + 4);
            unsigned long long u0 = *(const unsigned long long*)(opt + base);
            unsigned long long u1 = *(const unsigned long long*)(opt + base + 4);
            f32x4 d0 = *(const f32x4*)(dsb + cc);
            f32x4 d1 = *(const f32x4*)(dsb + cc + 4);
            float c0 = h0.x + wv*__uint_as_float((unsigned)(u0      & 0xffffull)<<16) + d0.x*cv;
            float c1 = h0.y + wv*__uint_as_float((unsigned)((u0>>16)& 0xffffull)<<16) + d0.y*cv;
            float c2 = h0.z + wv*__uint_as_float((unsigned)((u0>>32)& 0xffffull)<<16) + d0.z*cv;
            float c3 = h0.w + wv*__uint_as_float((unsigned)((u0>>48)& 0xffffull)<<16) + d0.w*cv;
            float c4 = h1.x + wv*__uint_as_float((unsigned)(u1      & 0xffffull)<<16) + d1.x*cv;
            float c5 = h1.y + wv*__uint_as_float((unsigned)((u1>>16)& 0xffffull)<<16) + d1.y*cv;
            float c6 = h1.z + wv*__uint_as_float((unsigned)((u1>>32)& 0xffffull)<<16) + d1.z*cv;
            float c7 = h1.w + wv*__uint_as_float((unsigned)((u1>>48)& 0xffffull)<<16) + d1.w*cv;
            o.x = pk2(c0,c1); o.y = pk2(c2,c3); o.z = pk2(c4,c5); o.w = pk2(c6,c7);
        }
        *(i32x4*)(&S[rq][cc]) = o;
    }
    __syncthreads();
    int w = tid>>6, lane = tid&63, lo = lane&15, hi = lane>>4;
    f32x4 acc[4][8];
    #pragma unroll
    for(int ms=0;ms<4;ms++){
        #pragma unroll
        for(int s=0;s<8;s++) acc[ms][s] = (f32x4){0.f,0.f,0.f,0.f};
    }
    asm volatile("s_nop 1" ::);
    for(int tap=0; tap<11; ++tap){
        const __hip_bfloat16* wtp = wt + (size_t)tap*262144 + (size_t)(w*128)*512;
        for(int kk=0; kk<512; kk+=32){
            i32x4 a[4];
            #pragma unroll
            for(int ms=0;ms<4;ms++) a[ms] = *(const i32x4*)(&S[ms*16 + lo + tap][kk + hi*8]);
            #pragma unroll
            for(int s=0;s<8;s++){
                i32x4 bq = *(const i32x4*)(wtp + (size_t)(s*16 + lo)*512 + kk + hi*8);
                #pragma unroll
                for(int ms=0;ms<4;ms++)
                    asm volatile("v_mfma_f32_16x16x32_bf16 %0, %1, %2, %0" : "+v"(acc[ms][s]) : "v"(a[ms]), "v"(bq));
            }
        }
    }
    asm volatile("s_nop 7\n\ts_nop 7" ::);
    #pragma unroll
    for(int s=0;s<8;s++){
        int co = w*128 + s*16 + lo;
        float cb = convb[co];
        #pragma unroll
        for(int ms=0;ms<4;ms++){
            #pragma unroll
            for(int rr=0; rr<4; ++rr){
                int row = ms*16 + hi*4 + rr;
                int tok = mt*64 + row;
                size_t gi = ((size_t)b*LSEQ + tok)*512 + co;
                float h   = hs[gi];
                float cef = __bfloat162float(S[row + 5][co]);
                outp[gi] = 0.5f*h + 0.3f*cef + 0.2f*(acc[ms][s][rr] + cb);
            }
        }
    }
}

// ================= launch =================
extern "C" void kernel_launch(void* const* d_in, const int* in_sizes, int n_in,
                              void* d_out, int out_size, void* d_ws, size_t ws_size,
                              hipStream_t stream)
{
    (void)in_sizes; (void)n_in; (void)out_size; (void)ws_size;
    const float* hidden = (const float*)d_in[0];
    const int*   aa     = (const int*)d_in[1];
    const float* Wbil   = (const float*)d_in[2];
    const float* bbil   = (const float*)d_in[3];
    const float* w1     = (const float*)d_in[4];
    const float* b1     = (const float*)d_in[5];
    const float* w2     = (const float*)d_in[6];
    const float* b2     = (const float*)d_in[7];
    const float* Wih    = (const float*)d_in[8];
    const float* Whh    = (const float*)d_in[9];
    const float* bih    = (const float*)d_in[10];
    const float* bhh    = (const float*)d_in[11];
    const float* convw  = (const float*)d_in[12];
    const float* convb  = (const float*)d_in[13];
    const float* dsb    = (const float*)d_in[14];

    float* outp = (float*)d_out;
    float* prob = outp + (size_t)NB*LSEQ*DDIM;
    float* sel  = prob + NB*KC*KC;

    char* p = (char*)d_ws;
    auto alloc = [&](size_t bytes)->char*{ char* r = p; p += (bytes + 255) & ~(size_t)255; return r; };
    __hip_bfloat16* gx    = (__hip_bfloat16*)alloc((size_t)16384*2048*2);
    __hip_bfloat16* hbf   = (__hip_bfloat16*)alloc((size_t)NB*LSEQ*DDIM*2);
    __hip_bfloat16* wihbf = (__hip_bfloat16*)alloc((size_t)2*2048*512*2);
    float*          bias2 = (float*)        alloc((size_t)2*2048*4);
    __hip_bfloat16* out1  = (__hip_bfloat16*)alloc((size_t)NB*LSEQ*DDIM*2);
    __hip_bfloat16* out2  = (__hip_bfloat16*)alloc((size_t)NB*LSEQ*DDIM*2);
    __hip_bfloat16* wtc   = (__hip_bfloat16*)alloc((size_t)11*512*512*2);
    float*          pf    = (float*)        alloc((size_t)NB*KC*KC*128*4);
    int*            pos   = (int*)          alloc((size_t)NB*KC*4);
    float*          cm    = (float*)        alloc((size_t)NB*LSEQ*4);
    float*          win   = (float*)        alloc((size_t)NB*LSEQ*4);

    // 1) prep: casts, bias, conv-w transpose, pos/cm/win
    k_prep<<<6168, 256, 0, stream>>>(hidden, hbf, Wih, wihbf, bih, bhh, bias2, convw, wtc, aa, pos, cm, win);
    // 2) Gx layer1
    k_gemm<<<dim3(16, 128), 256, 0, stream>>>(hbf, wihbf, bias2, gx, 2048, 512);
    // 3) recur layer1  ||  bilinear
    k_fused1<<<16 + 1024, 512, 0, stream>>>(Whh, gx, out1, hidden, pos, Wbil, bbil, pf);
    // 4) Gx layer2
    k_gemm<<<dim3(16, 128), 256, 0, stream>>>(out1, wihbf + (size_t)2048*512, bias2 + 2048, gx, 2048, 512);
    // 5) recur layer2  ||  cls+greedy
    k_fused2<<<16 + 8, 512, 0, stream>>>(Whh, gx, out2, pf, w1, b1, w2, b2, pos, prob, sel);
    // 6) conv (+ce) + final fusion
    k_convce<<<256, 256, 0, stream>>>(hidden, out2, win, cm, dsb, wtc, convb, outp);
}